// Round 1
// baseline (595.782 us; speedup 1.0000x reference)
//
#include <hip/hip_runtime.h>

// ---------- types / helpers ----------
typedef float f32x4 __attribute__((ext_vector_type(4)));
typedef short s16x8 __attribute__((ext_vector_type(8)));

#define MFMA16(a, b, c) __builtin_amdgcn_mfma_f32_16x16x32_bf16(a, b, c, 0, 0, 0)
#define SCALE 0.125f

__device__ __forceinline__ unsigned short f2bf(float f) {
    unsigned u = __float_as_uint(f);
    u = u + 0x7FFFu + ((u >> 16) & 1u);
    return (unsigned short)(u >> 16);
}

typedef const __attribute__((address_space(1))) void* gptr_t;
typedef __attribute__((address_space(3))) void* lptr_t;
__device__ __forceinline__ void gload16(const void* g, void* l) {
    __builtin_amdgcn_global_load_lds((gptr_t)g, (lptr_t)l, 16, 0, 0);
}

// ---------- convert x|skip concat -> bf16 [4096][2048] ----------
__global__ __launch_bounds__(256) void cvt_cat(const float* __restrict__ x,
                                               const float* __restrict__ skip,
                                               unsigned short* __restrict__ out) {
    const size_t i = ((size_t)blockIdx.x * 256 + threadIdx.x) * 8;
    const int r = (int)(i >> 11);
    const int c = (int)(i & 2047);
    const float* src = (c < 1024) ? (x + (size_t)r * 1024 + c)
                                  : (skip + (size_t)r * 1024 + (c - 1024));
    float4 v0 = *(const float4*)src;
    float4 v1 = *(const float4*)(src + 4);
    s16x8 o;
    o[0] = f2bf(v0.x); o[1] = f2bf(v0.y); o[2] = f2bf(v0.z); o[3] = f2bf(v0.w);
    o[4] = f2bf(v1.x); o[5] = f2bf(v1.y); o[6] = f2bf(v1.z); o[7] = f2bf(v1.w);
    *(s16x8*)(out + i) = o;
}

// ---------- fp32 [R][C] -> bf16 transpose [C][R] ----------
__global__ __launch_bounds__(256) void wt_tr(const float* __restrict__ in,
                                             unsigned short* __restrict__ out,
                                             int R, int C) {
    __shared__ unsigned short tile[64][72];
    const int nct = C >> 6;
    const int tr = blockIdx.x / nct, tc = blockIdx.x % nct;
    const int t = threadIdx.x;
    const int r = t >> 2, c0 = (t & 3) << 4;
    const float* src = in + (size_t)(tr * 64 + r) * C + tc * 64 + c0;
#pragma unroll
    for (int j = 0; j < 16; j += 4) {
        float4 v = *(const float4*)(src + j);
        tile[r][c0 + j]     = f2bf(v.x);
        tile[r][c0 + j + 1] = f2bf(v.y);
        tile[r][c0 + j + 2] = f2bf(v.z);
        tile[r][c0 + j + 3] = f2bf(v.w);
    }
    __syncthreads();
    const int oc = t >> 2, r0 = (t & 3) << 4;
    s16x8 o0, o1;
#pragma unroll
    for (int j = 0; j < 8; ++j) { o0[j] = tile[r0 + j][oc]; o1[j] = tile[r0 + 8 + j][oc]; }
    unsigned short* dst = out + (size_t)(tc * 64 + oc) * R + tr * 64 + r0;
    *(s16x8*)dst = o0;
    *(s16x8*)(dst + 8) = o1;
}

// ---------- V slice of qkv -> vt [B*H][64][1024] ----------
__global__ __launch_bounds__(256) void v_transpose(const unsigned short* __restrict__ qkv,
                                                   unsigned short* __restrict__ vt) {
    __shared__ unsigned short tile[64][72];
    const int bh = blockIdx.x >> 4, lt = blockIdx.x & 15;
    const int b = bh >> 4, h = bh & 15;
    const int t = threadIdx.x;
    const int r = t >> 2, c0 = (t & 3) << 4;
    const unsigned short* src =
        qkv + (size_t)(b * 1024 + lt * 64 + r) * 3072 + 2048 + h * 64 + c0;
    s16x8 v0 = *(const s16x8*)src;
    s16x8 v1 = *(const s16x8*)(src + 8);
#pragma unroll
    for (int j = 0; j < 8; ++j) { tile[r][c0 + j] = v0[j]; tile[r][c0 + 8 + j] = v1[j]; }
    __syncthreads();
    const int d = t >> 2, l0 = (t & 3) << 4;
    s16x8 o0, o1;
#pragma unroll
    for (int j = 0; j < 8; ++j) { o0[j] = tile[l0 + j][d]; o1[j] = tile[l0 + 8 + j][d]; }
    unsigned short* dst = vt + (size_t)bh * 65536 + (size_t)d * 1024 + lt * 64 + l0;
    *(s16x8*)dst = o0;
    *(s16x8*)(dst + 8) = o1;
}

// ---------- LayerNorm over rows of 1024, optional fp32 + bf16 outputs ----------
__global__ __launch_bounds__(256) void ln_kernel(const float* __restrict__ in,
                                                 const float* __restrict__ g,
                                                 const float* __restrict__ bb,
                                                 float* __restrict__ outf,
                                                 unsigned short* __restrict__ outb) {
    const int row = blockIdx.x;
    const int t = threadIdx.x;
    const float4 v = ((const float4*)(in + (size_t)row * 1024))[t];
    float s = v.x + v.y + v.z + v.w;
    float ss = v.x * v.x + v.y * v.y + v.z * v.z + v.w * v.w;
#pragma unroll
    for (int off = 1; off < 64; off <<= 1) {
        s += __shfl_xor(s, off, 64);
        ss += __shfl_xor(ss, off, 64);
    }
    __shared__ float red[8];
    const int wave = t >> 6, lane = t & 63;
    if (lane == 0) { red[wave] = s; red[4 + wave] = ss; }
    __syncthreads();
    s = red[0] + red[1] + red[2] + red[3];
    ss = red[4] + red[5] + red[6] + red[7];
    const float mean = s * 0.0009765625f;
    const float var = ss * 0.0009765625f - mean * mean;
    const float rstd = rsqrtf(var + 1e-5f);
    const float4 gv = ((const float4*)g)[t];
    const float4 bv = ((const float4*)bb)[t];
    float4 ov;
    ov.x = (v.x - mean) * rstd * gv.x + bv.x;
    ov.y = (v.y - mean) * rstd * gv.y + bv.y;
    ov.z = (v.z - mean) * rstd * gv.z + bv.z;
    ov.w = (v.w - mean) * rstd * gv.w + bv.w;
    if (outf) ((float4*)(outf + (size_t)row * 1024))[t] = ov;
    if (outb) {
        ushort4 ob;
        ob.x = f2bf(ov.x); ob.y = f2bf(ov.y); ob.z = f2bf(ov.z); ob.w = f2bf(ov.w);
        *(ushort4*)(outb + (size_t)row * 1024 + t * 4) = ob;
    }
}

// ---------- GEMM: C[M][N] = A[M][K](bf16) x Bt[N][K](bf16), templated epilogue ----------
// EPI 0: f32 out = acc + bias
// EPI 1: f32 out = acc + bias + resid
// EPI 2: bf16 out = acc            (no bias)
// EPI 3: bf16 out = gelu(acc+bias)
template <int EPI>
__global__ __launch_bounds__(256) void gemm_bt(const unsigned short* __restrict__ A,
                                               const unsigned short* __restrict__ Bt,
                                               void* __restrict__ outp,
                                               const float* __restrict__ bias,
                                               const float* __restrict__ resid,
                                               int M, int N, int K) {
    __shared__ __align__(16) unsigned short sA[2][128 * 32];
    __shared__ __align__(16) unsigned short sB[2][128 * 32];
    const int tid = threadIdx.x, wave = tid >> 6, lane = tid & 63;
    const int fr = lane & 15, fq = lane >> 4;
    const int nbn = N >> 7;
    const int bm = blockIdx.x / nbn, bn = blockIdx.x % nbn;
    const int wm = wave >> 1, wn = wave & 1;
    const unsigned short* Ab = A + (size_t)bm * 128 * K;
    const unsigned short* Bb = Bt + (size_t)bn * 128 * K;
    const int srow = wave * 32 + (lane >> 2);
    const int scol = (lane & 3) * 8;

    f32x4 acc[4][4];
#pragma unroll
    for (int i = 0; i < 4; ++i)
#pragma unroll
        for (int j = 0; j < 4; ++j) acc[i][j] = (f32x4){0.f, 0.f, 0.f, 0.f};

    auto stage = [&](int buf, int k0) {
        const unsigned short* ga = Ab + (size_t)srow * K + k0 + scol;
        const unsigned short* gb = Bb + (size_t)srow * K + k0 + scol;
        unsigned short* la = &sA[buf][wave * 32 * 32];
        unsigned short* lb = &sB[buf][wave * 32 * 32];
        gload16(ga, la);
        gload16(ga + (size_t)16 * K, la + 16 * 32);
        gload16(gb, lb);
        gload16(gb + (size_t)16 * K, lb + 16 * 32);
    };

    const int nkt = K >> 5;
    stage(0, 0);
    for (int kt = 0; kt < nkt; ++kt) {
        __syncthreads();
        if (kt + 1 < nkt) stage((kt + 1) & 1, (kt + 1) * 32);
        const unsigned short* a0 = &sA[kt & 1][0];
        const unsigned short* b0 = &sB[kt & 1][0];
        s16x8 af[4], bf[4];
#pragma unroll
        for (int i = 0; i < 4; ++i)
            af[i] = *(const s16x8*)(a0 + (wm * 64 + i * 16 + fr) * 32 + fq * 8);
#pragma unroll
        for (int j = 0; j < 4; ++j)
            bf[j] = *(const s16x8*)(b0 + (wn * 64 + j * 16 + fr) * 32 + fq * 8);
#pragma unroll
        for (int i = 0; i < 4; ++i)
#pragma unroll
            for (int j = 0; j < 4; ++j) acc[i][j] = MFMA16(af[i], bf[j], acc[i][j]);
    }

#pragma unroll
    for (int i = 0; i < 4; ++i) {
        const int row0 = bm * 128 + wm * 64 + i * 16 + fq * 4;
#pragma unroll
        for (int j = 0; j < 4; ++j) {
            const int col = bn * 128 + wn * 64 + j * 16 + fr;
            const float bv = (EPI == 2) ? 0.f : bias[col];
#pragma unroll
            for (int r = 0; r < 4; ++r) {
                const int row = row0 + r;
                float v = acc[i][j][r] + bv;
                if (EPI == 3) v = 0.5f * v * (1.f + erff(v * 0.70710678f));
                if (EPI == 1) v += resid[(size_t)row * N + col];
                if (EPI == 0 || EPI == 1)
                    ((float*)outp)[(size_t)row * N + col] = v;
                else
                    ((unsigned short*)outp)[(size_t)row * N + col] = f2bf(v);
            }
        }
    }
}

// ---------- attention: qkv bf16 [4096][3072], vt [B*H][64][1024] -> o bf16 [4096][1024]
__global__ __launch_bounds__(256) void attn_kernel(const unsigned short* __restrict__ qkv,
                                                   const unsigned short* __restrict__ vt,
                                                   unsigned short* __restrict__ o) {
    __shared__ __align__(16) unsigned short pbuf[4][16 * 72];
    const int bh = blockIdx.x >> 4, qt = blockIdx.x & 15;
    const int b = bh >> 4, h = bh & 15;
    const int wave = threadIdx.x >> 6, lane = threadIdx.x & 63;
    const int fr = lane & 15, fq = lane >> 4;
    const int qrow0 = b * 1024 + qt * 64 + wave * 16;
    const unsigned short* qp = qkv + (size_t)(qrow0 + fr) * 3072 + h * 64;
    const s16x8 aq0 = *(const s16x8*)(qp + fq * 8);
    const s16x8 aq1 = *(const s16x8*)(qp + 32 + fq * 8);
    float m[4], l[4];
    f32x4 oacc[4];
#pragma unroll
    for (int r = 0; r < 4; ++r) { m[r] = -1e30f; l[r] = 0.f; }
#pragma unroll
    for (int n = 0; n < 4; ++n) oacc[n] = (f32x4){0.f, 0.f, 0.f, 0.f};
    unsigned short* pw = &pbuf[wave][0];
    const unsigned short* kbase = qkv + (size_t)(b * 1024) * 3072 + 1024 + h * 64;
    const unsigned short* vbase = vt + (size_t)bh * 65536;

    for (int kt = 0; kt < 16; ++kt) {
        f32x4 s[4];
#pragma unroll
        for (int n = 0; n < 4; ++n) s[n] = (f32x4){0.f, 0.f, 0.f, 0.f};
#pragma unroll
        for (int n = 0; n < 4; ++n) {
            const unsigned short* kp = kbase + (size_t)(kt * 64 + n * 16 + fr) * 3072;
            const s16x8 bk0 = *(const s16x8*)(kp + fq * 8);
            const s16x8 bk1 = *(const s16x8*)(kp + 32 + fq * 8);
            s[n] = MFMA16(aq0, bk0, s[n]);
            s[n] = MFMA16(aq1, bk1, s[n]);
        }
        float mnew[4], alpha[4], rs[4];
#pragma unroll
        for (int r = 0; r < 4; ++r) {
            float t = fmaxf(fmaxf(s[0][r], s[1][r]), fmaxf(s[2][r], s[3][r])) * SCALE;
#pragma unroll
            for (int off = 1; off < 16; off <<= 1) t = fmaxf(t, __shfl_xor(t, off, 64));
            mnew[r] = fmaxf(m[r], t);
            alpha[r] = __expf(m[r] - mnew[r]);
            rs[r] = 0.f;
        }
#pragma unroll
        for (int n = 0; n < 4; ++n) {
#pragma unroll
            for (int r = 0; r < 4; ++r) {
                const float p = __expf(s[n][r] * SCALE - mnew[r]);
                rs[r] += p;
                pw[(fq * 4 + r) * 72 + n * 16 + fr] = f2bf(p);
            }
        }
#pragma unroll
        for (int r = 0; r < 4; ++r) {
            float t = rs[r];
#pragma unroll
            for (int off = 1; off < 16; off <<= 1) t += __shfl_xor(t, off, 64);
            l[r] = l[r] * alpha[r] + t;
            m[r] = mnew[r];
        }
#pragma unroll
        for (int n = 0; n < 4; ++n) {
            oacc[n][0] *= alpha[0]; oacc[n][1] *= alpha[1];
            oacc[n][2] *= alpha[2]; oacc[n][3] *= alpha[3];
        }
        __syncthreads();  // P writes visible (cross-lane LDS RAW)
        const s16x8 ap0 = *(const s16x8*)(pw + fr * 72 + fq * 8);
        const s16x8 ap1 = *(const s16x8*)(pw + fr * 72 + 32 + fq * 8);
#pragma unroll
        for (int n = 0; n < 4; ++n) {
            const unsigned short* vp = vbase + (size_t)(n * 16 + fr) * 1024 + kt * 64;
            const s16x8 bv0 = *(const s16x8*)(vp + fq * 8);
            const s16x8 bv1 = *(const s16x8*)(vp + 32 + fq * 8);
            oacc[n] = MFMA16(ap0, bv0, oacc[n]);
            oacc[n] = MFMA16(ap1, bv1, oacc[n]);
        }
        __syncthreads();  // protect P buffer WAR before next tile's writes
    }
#pragma unroll
    for (int n = 0; n < 4; ++n) {
#pragma unroll
        for (int r = 0; r < 4; ++r) {
            const int row = qrow0 + fq * 4 + r;
            const int col = h * 64 + n * 16 + fr;
            o[(size_t)row * 1024 + col] = f2bf(oacc[n][r] / l[r]);
        }
    }
}

// ---------- launcher ----------
extern "C" void kernel_launch(void* const* d_in, const int* in_sizes, int n_in,
                              void* d_out, int out_size, void* d_ws, size_t ws_size,
                              hipStream_t stream) {
    (void)in_sizes; (void)n_in; (void)out_size; (void)ws_size;
    const float* x      = (const float*)d_in[0];
    const float* skip   = (const float*)d_in[1];
    const float* skip_w = (const float*)d_in[2];
    const float* skip_b = (const float*)d_in[3];
    const float* ln1_g  = (const float*)d_in[4];
    const float* ln1_b  = (const float*)d_in[5];
    const float* qkv_w  = (const float*)d_in[6];
    const float* proj_w = (const float*)d_in[7];
    const float* proj_b = (const float*)d_in[8];
    const float* ln2_g  = (const float*)d_in[9];
    const float* ln2_b  = (const float*)d_in[10];
    const float* fc1_w  = (const float*)d_in[11];
    const float* fc1_b  = (const float*)d_in[12];
    const float* fc2_w  = (const float*)d_in[13];
    const float* fc2_b  = (const float*)d_in[14];
    const float* ln3_g  = (const float*)d_in[15];
    const float* ln3_b  = (const float*)d_in[16];

    char* ws = (char*)d_ws;
    const size_t MB = 1u << 20;
    unsigned short* skip_wT = (unsigned short*)(ws + 0 * MB);    // 4MB  [1024][2048]
    unsigned short* qkv_wT  = (unsigned short*)(ws + 4 * MB);    // 6MB  [3072][1024]
    unsigned short* proj_wT = (unsigned short*)(ws + 10 * MB);   // 2MB  [1024][1024]
    unsigned short* fc1_wT  = (unsigned short*)(ws + 12 * MB);   // 8MB  [4096][1024]
    unsigned short* fc2_wT  = (unsigned short*)(ws + 20 * MB);   // 8MB  [1024][4096]
    float* pre              = (float*)(ws + 28 * MB);            // 16MB [4096][1024] f32
    float* x1               = (float*)(ws + 44 * MB);            // 16MB
    unsigned short* x1b     = (unsigned short*)(ws + 60 * MB);   // 8MB
    unsigned short* qkvb    = (unsigned short*)(ws + 68 * MB);   // 24MB [4096][3072]
    float* x2n              = (float*)(ws + 68 * MB);            // aliases qkvb (dead by LN2)
    unsigned short* x2nb    = (unsigned short*)(ws + 84 * MB);   // 8MB (in old qkvb)
    unsigned short* vtb     = (unsigned short*)(ws + 92 * MB);   // 8MB [64][64][1024]
    unsigned short* ob      = (unsigned short*)(ws + 100 * MB);  // 8MB [4096][1024]
    unsigned short* hb      = (unsigned short*)(ws + 108 * MB);  // 32MB [4096][4096]
    unsigned short* xcatb   = (unsigned short*)(ws + 108 * MB);  // aliases hb (dead by fc1)
    float* outf = (float*)d_out;

    // weight conversions / transposes
    cvt_cat<<<4096, 256, 0, stream>>>(x, skip, xcatb);
    wt_tr<<<512, 256, 0, stream>>>(skip_w, skip_wT, 2048, 1024);
    wt_tr<<<768, 256, 0, stream>>>(qkv_w, qkv_wT, 1024, 3072);
    wt_tr<<<256, 256, 0, stream>>>(proj_w, proj_wT, 1024, 1024);
    wt_tr<<<1024, 256, 0, stream>>>(fc1_w, fc1_wT, 1024, 4096);
    wt_tr<<<1024, 256, 0, stream>>>(fc2_w, fc2_wT, 4096, 1024);

    // skip-cat GEMM -> pre ; LN1 -> x1 (f32) + x1b (bf16)
    gemm_bt<0><<<32 * 8, 256, 0, stream>>>(xcatb, skip_wT, pre, skip_b, nullptr, 4096, 1024, 2048);
    ln_kernel<<<4096, 256, 0, stream>>>(pre, ln1_g, ln1_b, x1, x1b);

    // qkv GEMM (bf16 out, no bias)
    gemm_bt<2><<<32 * 24, 256, 0, stream>>>(x1b, qkv_wT, qkvb, nullptr, nullptr, 4096, 3072, 1024);

    // attention
    v_transpose<<<1024, 256, 0, stream>>>(qkvb, vtb);
    attn_kernel<<<1024, 256, 0, stream>>>(qkvb, vtb, ob);

    // proj GEMM + bias + residual(x1) -> pre ; LN2 -> x2n + x2nb
    gemm_bt<1><<<32 * 8, 256, 0, stream>>>(ob, proj_wT, pre, proj_b, x1, 4096, 1024, 1024);
    ln_kernel<<<4096, 256, 0, stream>>>(pre, ln2_g, ln2_b, x2n, x2nb);

    // fc1 GEMM + bias + GELU -> h (bf16)
    gemm_bt<3><<<32 * 32, 256, 0, stream>>>(x2nb, fc1_wT, hb, fc1_b, nullptr, 4096, 4096, 1024);

    // fc2 GEMM + bias + residual(x2n) -> pre ; LN3 -> d_out (f32)
    gemm_bt<1><<<32 * 8, 256, 0, stream>>>(hb, fc2_wT, pre, fc2_b, x2n, 4096, 1024, 4096);
    ln_kernel<<<4096, 256, 0, stream>>>(pre, ln3_g, ln3_b, outf, nullptr);
}

// Round 3
// 505.578 us; speedup vs baseline: 1.1784x; 1.1784x over previous
//
#include <hip/hip_runtime.h>

// ---------- types / helpers ----------
typedef float f32x4 __attribute__((ext_vector_type(4)));
typedef short s16x8 __attribute__((ext_vector_type(8)));

#define MFMA16(a, b, c) __builtin_amdgcn_mfma_f32_16x16x32_bf16(a, b, c, 0, 0, 0)
#define SCALE 0.125f

__device__ __forceinline__ unsigned short f2bf(float f) {
    unsigned u = __float_as_uint(f);
    u = u + 0x7FFFu + ((u >> 16) & 1u);
    return (unsigned short)(u >> 16);
}

typedef const __attribute__((address_space(1))) void* gptr_t;
typedef __attribute__((address_space(3))) void* lptr_t;
__device__ __forceinline__ void gload16(const void* g, void* l) {
    __builtin_amdgcn_global_load_lds((gptr_t)g, (lptr_t)l, 16, 0, 0);
}

// ---------- convert x|skip concat -> bf16 [4096][2048] ----------
__global__ __launch_bounds__(256) void cvt_cat(const float* __restrict__ x,
                                               const float* __restrict__ skip,
                                               unsigned short* __restrict__ out) {
    const size_t i = ((size_t)blockIdx.x * 256 + threadIdx.x) * 8;
    const int r = (int)(i >> 11);
    const int c = (int)(i & 2047);
    const float* src = (c < 1024) ? (x + (size_t)r * 1024 + c)
                                  : (skip + (size_t)r * 1024 + (c - 1024));
    float4 v0 = *(const float4*)src;
    float4 v1 = *(const float4*)(src + 4);
    s16x8 o;
    o[0] = f2bf(v0.x); o[1] = f2bf(v0.y); o[2] = f2bf(v0.z); o[3] = f2bf(v0.w);
    o[4] = f2bf(v1.x); o[5] = f2bf(v1.y); o[6] = f2bf(v1.z); o[7] = f2bf(v1.w);
    *(s16x8*)(out + i) = o;
}

// ---------- fp32 [R][C] -> bf16 transpose [C][R] ----------
__global__ __launch_bounds__(256) void wt_tr(const float* __restrict__ in,
                                             unsigned short* __restrict__ out,
                                             int R, int C) {
    __shared__ unsigned short tile[64][72];
    const int nct = C >> 6;
    const int tr = blockIdx.x / nct, tc = blockIdx.x % nct;
    const int t = threadIdx.x;
    const int r = t >> 2, c0 = (t & 3) << 4;
    const float* src = in + (size_t)(tr * 64 + r) * C + tc * 64 + c0;
#pragma unroll
    for (int j = 0; j < 16; j += 4) {
        float4 v = *(const float4*)(src + j);
        tile[r][c0 + j]     = f2bf(v.x);
        tile[r][c0 + j + 1] = f2bf(v.y);
        tile[r][c0 + j + 2] = f2bf(v.z);
        tile[r][c0 + j + 3] = f2bf(v.w);
    }
    __syncthreads();
    const int oc = t >> 2, r0 = (t & 3) << 4;
    s16x8 o0, o1;
#pragma unroll
    for (int j = 0; j < 8; ++j) { o0[j] = tile[r0 + j][oc]; o1[j] = tile[r0 + 8 + j][oc]; }
    unsigned short* dst = out + (size_t)(tc * 64 + oc) * R + tr * 64 + r0;
    *(s16x8*)dst = o0;
    *(s16x8*)(dst + 8) = o1;
}

// ---------- V slice of qkv -> vt [B*H][64][1024] ----------
__global__ __launch_bounds__(256) void v_transpose(const unsigned short* __restrict__ qkv,
                                                   unsigned short* __restrict__ vt) {
    __shared__ unsigned short tile[64][72];
    const int bh = blockIdx.x >> 4, lt = blockIdx.x & 15;
    const int b = bh >> 4, h = bh & 15;
    const int t = threadIdx.x;
    const int r = t >> 2, c0 = (t & 3) << 4;
    const unsigned short* src =
        qkv + (size_t)(b * 1024 + lt * 64 + r) * 3072 + 2048 + h * 64 + c0;
    s16x8 v0 = *(const s16x8*)src;
    s16x8 v1 = *(const s16x8*)(src + 8);
#pragma unroll
    for (int j = 0; j < 8; ++j) { tile[r][c0 + j] = v0[j]; tile[r][c0 + 8 + j] = v1[j]; }
    __syncthreads();
    const int d = t >> 2, l0 = (t & 3) << 4;
    s16x8 o0, o1;
#pragma unroll
    for (int j = 0; j < 8; ++j) { o0[j] = tile[l0 + j][d]; o1[j] = tile[l0 + 8 + j][d]; }
    unsigned short* dst = vt + (size_t)bh * 65536 + (size_t)d * 1024 + lt * 64 + l0;
    *(s16x8*)dst = o0;
    *(s16x8*)(dst + 8) = o1;
}

// ---------- LayerNorm over rows of 1024, optional fp32 + bf16 outputs ----------
__global__ __launch_bounds__(256) void ln_kernel(const float* __restrict__ in,
                                                 const float* __restrict__ g,
                                                 const float* __restrict__ bb,
                                                 float* __restrict__ outf,
                                                 unsigned short* __restrict__ outb) {
    const int row = blockIdx.x;
    const int t = threadIdx.x;
    const float4 v = ((const float4*)(in + (size_t)row * 1024))[t];
    float s = v.x + v.y + v.z + v.w;
    float ss = v.x * v.x + v.y * v.y + v.z * v.z + v.w * v.w;
#pragma unroll
    for (int off = 1; off < 64; off <<= 1) {
        s += __shfl_xor(s, off, 64);
        ss += __shfl_xor(ss, off, 64);
    }
    __shared__ float red[8];
    const int wave = t >> 6, lane = t & 63;
    if (lane == 0) { red[wave] = s; red[4 + wave] = ss; }
    __syncthreads();
    s = red[0] + red[1] + red[2] + red[3];
    ss = red[4] + red[5] + red[6] + red[7];
    const float mean = s * 0.0009765625f;
    const float var = ss * 0.0009765625f - mean * mean;
    const float rstd = rsqrtf(var + 1e-5f);
    const float4 gv = ((const float4*)g)[t];
    const float4 bv = ((const float4*)bb)[t];
    float4 ov;
    ov.x = (v.x - mean) * rstd * gv.x + bv.x;
    ov.y = (v.y - mean) * rstd * gv.y + bv.y;
    ov.z = (v.z - mean) * rstd * gv.z + bv.z;
    ov.w = (v.w - mean) * rstd * gv.w + bv.w;
    if (outf) ((float4*)(outf + (size_t)row * 1024))[t] = ov;
    if (outb) {
        ushort4 ob;
        ob.x = f2bf(ov.x); ob.y = f2bf(ov.y); ob.z = f2bf(ov.z); ob.w = f2bf(ov.w);
        *(ushort4*)(outb + (size_t)row * 1024 + t * 4) = ob;
    }
}

// ---------- GEMM: C[M][N] = A[M][K](bf16) x Bt[N][K](bf16), templated epilogue ----------
// EPI 0: f32 out = acc + bias
// EPI 1: f32 out = acc + bias + resid
// EPI 2: bf16 out = acc            (no bias)
// EPI 3: bf16 out = gelu(acc+bias)
template <int EPI>
__global__ __launch_bounds__(256) void gemm_bt(const unsigned short* __restrict__ A,
                                               const unsigned short* __restrict__ Bt,
                                               void* __restrict__ outp,
                                               const float* __restrict__ bias,
                                               const float* __restrict__ resid,
                                               int M, int N, int K) {
    __shared__ __align__(16) unsigned short sA[2][128 * 32];
    __shared__ __align__(16) unsigned short sB[2][128 * 32];
    const int tid = threadIdx.x, wave = tid >> 6, lane = tid & 63;
    const int fr = lane & 15, fq = lane >> 4;
    const int nbn = N >> 7;
    const int bm = blockIdx.x / nbn, bn = blockIdx.x % nbn;
    const int wm = wave >> 1, wn = wave & 1;
    const unsigned short* Ab = A + (size_t)bm * 128 * K;
    const unsigned short* Bb = Bt + (size_t)bn * 128 * K;
    const int srow = wave * 32 + (lane >> 2);
    const int scol = (lane & 3) * 8;

    f32x4 acc[4][4];
#pragma unroll
    for (int i = 0; i < 4; ++i)
#pragma unroll
        for (int j = 0; j < 4; ++j) acc[i][j] = (f32x4){0.f, 0.f, 0.f, 0.f};

    auto stage = [&](int buf, int k0) {
        const unsigned short* ga = Ab + (size_t)srow * K + k0 + scol;
        const unsigned short* gb = Bb + (size_t)srow * K + k0 + scol;
        unsigned short* la = &sA[buf][wave * 32 * 32];
        unsigned short* lb = &sB[buf][wave * 32 * 32];
        gload16(ga, la);
        gload16(ga + (size_t)16 * K, la + 16 * 32);
        gload16(gb, lb);
        gload16(gb + (size_t)16 * K, lb + 16 * 32);
    };

    const int nkt = K >> 5;
    stage(0, 0);
    for (int kt = 0; kt < nkt; ++kt) {
        __syncthreads();
        if (kt + 1 < nkt) stage((kt + 1) & 1, (kt + 1) * 32);
        const unsigned short* a0 = &sA[kt & 1][0];
        const unsigned short* b0 = &sB[kt & 1][0];
        s16x8 af[4], bf[4];
#pragma unroll
        for (int i = 0; i < 4; ++i)
            af[i] = *(const s16x8*)(a0 + (wm * 64 + i * 16 + fr) * 32 + fq * 8);
#pragma unroll
        for (int j = 0; j < 4; ++j)
            bf[j] = *(const s16x8*)(b0 + (wn * 64 + j * 16 + fr) * 32 + fq * 8);
#pragma unroll
        for (int i = 0; i < 4; ++i)
#pragma unroll
            for (int j = 0; j < 4; ++j) acc[i][j] = MFMA16(af[i], bf[j], acc[i][j]);
    }

#pragma unroll
    for (int i = 0; i < 4; ++i) {
        const int row0 = bm * 128 + wm * 64 + i * 16 + fq * 4;
#pragma unroll
        for (int j = 0; j < 4; ++j) {
            const int col = bn * 128 + wn * 64 + j * 16 + fr;
            const float bv = (EPI == 2) ? 0.f : bias[col];
#pragma unroll
            for (int r = 0; r < 4; ++r) {
                const int row = row0 + r;
                float v = acc[i][j][r] + bv;
                if (EPI == 3) v = 0.5f * v * (1.f + erff(v * 0.70710678f));
                if (EPI == 1) v += resid[(size_t)row * N + col];
                if (EPI == 0 || EPI == 1)
                    ((float*)outp)[(size_t)row * N + col] = v;
                else
                    ((unsigned short*)outp)[(size_t)row * N + col] = f2bf(v);
            }
        }
    }
}

// ---------- attention (flash, LDS-staged K/V, swizzled) ----------
// qkv bf16 [4096][3072], vt [B*H][64][1024] -> o bf16 [4096][1024]
// block = (bh, qt): 64 q-rows, 4 waves x 16 q-rows. K-tile/V-tile 64x64 staged
// in LDS double-buffered via global_load_lds (linear dest, pre-swizzled global
// source per m104/m173); XOR swizzle (row&7)<<4 on byte offset kills the
// stride-128B ds_read_b128 bank conflict (T2). P is wave-private LDS (no
// barriers needed; lgkmcnt orders ds_write->ds_read within the wave).
__global__ __launch_bounds__(256) void attn_kernel(const unsigned short* __restrict__ qkv,
                                                   const unsigned short* __restrict__ vt,
                                                   unsigned short* __restrict__ o) {
    __shared__ __align__(16) unsigned short sK[2][64 * 64];
    __shared__ __align__(16) unsigned short sV[2][64 * 64];
    __shared__ __align__(16) unsigned short sP[4][16 * 64];

    // XCD-chunked remap: all 16 q-tiles of one (b,h) land on one XCD's L2.
    const int j = blockIdx.x;
    const int xcd = j & 7, ix = j >> 3;      // ix in [0,128)
    const int bh = xcd * 8 + (ix >> 4);      // 8 bh per XCD
    const int qt = ix & 15;
    const int b = bh >> 4, h = bh & 15;

    const int tid = threadIdx.x;
    const int wave = tid >> 6, lane = tid & 63;
    const int fr = lane & 15, fq = lane >> 4;

    const unsigned short* kbase = qkv + (size_t)(b * 1024) * 3072 + 1024 + h * 64;
    const unsigned short* vbase = vt + (size_t)bh * 65536;

    // Q fragments (once per block; scattered but negligible)
    const int qrow0 = b * 1024 + qt * 64 + wave * 16;
    const unsigned short* qp = qkv + (size_t)(qrow0 + fr) * 3072 + h * 64;
    const s16x8 aq0 = *(const s16x8*)(qp + fq * 8);
    const s16x8 aq1 = *(const s16x8*)(qp + 32 + fq * 8);

    const f32x4 zero4 = {0.f, 0.f, 0.f, 0.f};
    float m[4], l[4];
    f32x4 oacc[4];
#pragma unroll
    for (int r = 0; r < 4; ++r) { m[r] = -1e30f; l[r] = 0.f; }
#pragma unroll
    for (int n = 0; n < 4; ++n) oacc[n] = zero4;

    // stage: linear LDS dest (base + tid*16), global source col pre-swizzled
    auto stage = [&](int buf, int kt) {
#pragma unroll
        for (int c = 0; c < 2; ++c) {
            const int ob = tid * 16 + c * 4096;        // byte off in 8KB tile
            const int row = ob >> 7;                   // 0..63
            const int slot = (ob >> 4) & 7;            // 16B slot in 128B row
            const int cole = ((slot ^ (row & 7)) << 3); // element col
            gload16(kbase + (size_t)(kt * 64 + row) * 3072 + cole,
                    (char*)&sK[buf][0] + ob);
            gload16(vbase + (size_t)row * 1024 + kt * 64 + cole,
                    (char*)&sV[buf][0] + ob);
        }
    };

    unsigned short* pw = &sP[wave][0];
    const int psw = (fr & 7) << 4;  // P-read xor (bytes)

    stage(0, 0);
    for (int kt = 0; kt < 16; ++kt) {
        const int cur = kt & 1;
        __syncthreads();                       // stage(cur) visible (vmcnt drained)
        if (kt + 1 < 16) stage(cur ^ 1, kt + 1);

        // ---- QK^T ----
        const unsigned short* kb = &sK[cur][0];
        f32x4 s[4];
        __builtin_amdgcn_s_setprio(1);
#pragma unroll
        for (int n = 0; n < 4; ++n) {
            const int R = n * 16 + fr;
            const int sw = (R & 7) << 3;       // element xor within 64-elem row
            const s16x8 bk0 = *(const s16x8*)(kb + R * 64 + ((fq * 8) ^ sw));
            const s16x8 bk1 = *(const s16x8*)(kb + R * 64 + ((32 + fq * 8) ^ sw));
            s[n] = MFMA16(aq0, bk0, zero4);
            s[n] = MFMA16(aq1, bk1, s[n]);
        }
        __builtin_amdgcn_s_setprio(0);

        // ---- online softmax ----
        float mnew[4], alpha[4], rs[4];
#pragma unroll
        for (int r = 0; r < 4; ++r) {
            float t = fmaxf(fmaxf(s[0][r], s[1][r]), fmaxf(s[2][r], s[3][r])) * SCALE;
#pragma unroll
            for (int off = 1; off < 16; off <<= 1) t = fmaxf(t, __shfl_xor(t, off, 64));
            mnew[r] = fmaxf(m[r], t);
            alpha[r] = __expf(m[r] - mnew[r]);
            rs[r] = 0.f;
        }
#pragma unroll
        for (int n = 0; n < 4; ++n) {
#pragma unroll
            for (int r = 0; r < 4; ++r) {
                const float p = __expf(s[n][r] * SCALE - mnew[r]);
                rs[r] += p;
                const int prow = fq * 4 + r;
                const int pb = prow * 128 + (((n * 16 + fr) * 2) ^ ((prow & 7) << 4));
                *(unsigned short*)((char*)pw + pb) = f2bf(p);
            }
        }
#pragma unroll
        for (int r = 0; r < 4; ++r) {
            float t = rs[r];
#pragma unroll
            for (int off = 1; off < 16; off <<= 1) t += __shfl_xor(t, off, 64);
            l[r] = l[r] * alpha[r] + t;
            m[r] = mnew[r];
        }
#pragma unroll
        for (int n = 0; n < 4; ++n) {
            oacc[n][0] *= alpha[0]; oacc[n][1] *= alpha[1];
            oacc[n][2] *= alpha[2]; oacc[n][3] *= alpha[3];
        }

        // ---- PV ---- (P is wave-private: no barrier, lgkmcnt orders it)
        const s16x8 ap0 = *(const s16x8*)((char*)pw + fr * 128 + ((fq * 16) ^ psw));
        const s16x8 ap1 = *(const s16x8*)((char*)pw + fr * 128 + ((64 + fq * 16) ^ psw));
        const unsigned short* vb = &sV[cur][0];
        __builtin_amdgcn_s_setprio(1);
#pragma unroll
        for (int n = 0; n < 4; ++n) {
            const int R = n * 16 + fr;
            const int sw = (R & 7) << 3;
            const s16x8 bv0 = *(const s16x8*)(vb + R * 64 + ((fq * 8) ^ sw));
            const s16x8 bv1 = *(const s16x8*)(vb + R * 64 + ((32 + fq * 8) ^ sw));
            oacc[n] = MFMA16(ap0, bv0, oacc[n]);
            oacc[n] = MFMA16(ap1, bv1, oacc[n]);
        }
        __builtin_amdgcn_s_setprio(0);
    }

#pragma unroll
    for (int r = 0; r < 4; ++r) {
        const float rl = 1.f / l[r];
        const int row = qrow0 + fq * 4 + r;
#pragma unroll
        for (int n = 0; n < 4; ++n) {
            const int col = h * 64 + n * 16 + fr;
            o[(size_t)row * 1024 + col] = f2bf(oacc[n][r] * rl);
        }
    }
}

// ---------- launcher ----------
extern "C" void kernel_launch(void* const* d_in, const int* in_sizes, int n_in,
                              void* d_out, int out_size, void* d_ws, size_t ws_size,
                              hipStream_t stream) {
    (void)in_sizes; (void)n_in; (void)out_size; (void)ws_size;
    const float* x      = (const float*)d_in[0];
    const float* skip   = (const float*)d_in[1];
    const float* skip_w = (const float*)d_in[2];
    const float* skip_b = (const float*)d_in[3];
    const float* ln1_g  = (const float*)d_in[4];
    const float* ln1_b  = (const float*)d_in[5];
    const float* qkv_w  = (const float*)d_in[6];
    const float* proj_w = (const float*)d_in[7];
    const float* proj_b = (const float*)d_in[8];
    const float* ln2_g  = (const float*)d_in[9];
    const float* ln2_b  = (const float*)d_in[10];
    const float* fc1_w  = (const float*)d_in[11];
    const float* fc1_b  = (const float*)d_in[12];
    const float* fc2_w  = (const float*)d_in[13];
    const float* fc2_b  = (const float*)d_in[14];
    const float* ln3_g  = (const float*)d_in[15];
    const float* ln3_b  = (const float*)d_in[16];

    char* ws = (char*)d_ws;
    const size_t MB = 1u << 20;
    unsigned short* skip_wT = (unsigned short*)(ws + 0 * MB);    // 4MB  [1024][2048]
    unsigned short* qkv_wT  = (unsigned short*)(ws + 4 * MB);    // 6MB  [3072][1024]
    unsigned short* proj_wT = (unsigned short*)(ws + 10 * MB);   // 2MB  [1024][1024]
    unsigned short* fc1_wT  = (unsigned short*)(ws + 12 * MB);   // 8MB  [4096][1024]
    unsigned short* fc2_wT  = (unsigned short*)(ws + 20 * MB);   // 8MB  [1024][4096]
    float* pre              = (float*)(ws + 28 * MB);            // 16MB [4096][1024] f32
    float* x1               = (float*)(ws + 44 * MB);            // 16MB
    unsigned short* x1b     = (unsigned short*)(ws + 60 * MB);   // 8MB
    unsigned short* qkvb    = (unsigned short*)(ws + 68 * MB);   // 24MB [4096][3072]
    float* x2n              = (float*)(ws + 68 * MB);            // aliases qkvb (dead by LN2)
    unsigned short* x2nb    = (unsigned short*)(ws + 84 * MB);   // 8MB (in old qkvb)
    unsigned short* vtb     = (unsigned short*)(ws + 92 * MB);   // 8MB [64][64][1024]
    unsigned short* ob      = (unsigned short*)(ws + 100 * MB);  // 8MB [4096][1024]
    unsigned short* hb      = (unsigned short*)(ws + 108 * MB);  // 32MB [4096][4096]
    unsigned short* xcatb   = (unsigned short*)(ws + 108 * MB);  // aliases hb (dead by fc1)
    float* outf = (float*)d_out;

    // weight conversions / transposes
    cvt_cat<<<4096, 256, 0, stream>>>(x, skip, xcatb);
    wt_tr<<<512, 256, 0, stream>>>(skip_w, skip_wT, 2048, 1024);
    wt_tr<<<768, 256, 0, stream>>>(qkv_w, qkv_wT, 1024, 3072);
    wt_tr<<<256, 256, 0, stream>>>(proj_w, proj_wT, 1024, 1024);
    wt_tr<<<1024, 256, 0, stream>>>(fc1_w, fc1_wT, 1024, 4096);
    wt_tr<<<1024, 256, 0, stream>>>(fc2_w, fc2_wT, 4096, 1024);

    // skip-cat GEMM -> pre ; LN1 -> x1 (f32) + x1b (bf16)
    gemm_bt<0><<<32 * 8, 256, 0, stream>>>(xcatb, skip_wT, pre, skip_b, nullptr, 4096, 1024, 2048);
    ln_kernel<<<4096, 256, 0, stream>>>(pre, ln1_g, ln1_b, x1, x1b);

    // qkv GEMM (bf16 out, no bias)
    gemm_bt<2><<<32 * 24, 256, 0, stream>>>(x1b, qkv_wT, qkvb, nullptr, nullptr, 4096, 3072, 1024);

    // attention
    v_transpose<<<1024, 256, 0, stream>>>(qkvb, vtb);
    attn_kernel<<<1024, 256, 0, stream>>>(qkvb, vtb, ob);

    // proj GEMM + bias + residual(x1) -> pre ; LN2 -> x2n + x2nb
    gemm_bt<1><<<32 * 8, 256, 0, stream>>>(ob, proj_wT, pre, proj_b, x1, 4096, 1024, 1024);
    ln_kernel<<<4096, 256, 0, stream>>>(pre, ln2_g, ln2_b, x2n, x2nb);

    // fc1 GEMM + bias + GELU -> h (bf16)
    gemm_bt<3><<<32 * 32, 256, 0, stream>>>(x2nb, fc1_wT, hb, fc1_b, nullptr, 4096, 4096, 1024);

    // fc2 GEMM + bias + residual(x2n) -> pre ; LN3 -> d_out (f32)
    gemm_bt<1><<<32 * 8, 256, 0, stream>>>(hb, fc2_wT, pre, fc2_b, x2n, 4096, 1024, 4096);
    ln_kernel<<<4096, 256, 0, stream>>>(pre, ln3_g, ln3_b, outf, nullptr);
}

// Round 4
// 491.491 us; speedup vs baseline: 1.2122x; 1.0287x over previous
//
#include <hip/hip_runtime.h>

// ---------- types / helpers ----------
typedef float f32x4 __attribute__((ext_vector_type(4)));
typedef short s16x8 __attribute__((ext_vector_type(8)));

#define MFMA16(a, b, c) __builtin_amdgcn_mfma_f32_16x16x32_bf16(a, b, c, 0, 0, 0)
#define SCALE 0.125f

__device__ __forceinline__ unsigned short f2bf(float f) {
    unsigned u = __float_as_uint(f);
    u = u + 0x7FFFu + ((u >> 16) & 1u);
    return (unsigned short)(u >> 16);
}

// clamped tanh-GELU via exp: gelu(x) ~= x * sigmoid(1.5957691(x + 0.044715 x^3))
__device__ __forceinline__ float fast_gelu(float x) {
    float u = 1.5957691216f * (x + 0.044715f * x * x * x);
    u = fminf(u, 30.f);                 // avoid inf/inf
    const float e = __expf(u);
    return x * e / (e + 1.f);
}

typedef const __attribute__((address_space(1))) void* gptr_t;
typedef __attribute__((address_space(3))) void* lptr_t;
__device__ __forceinline__ void gload16(const void* g, void* l) {
    __builtin_amdgcn_global_load_lds((gptr_t)g, (lptr_t)l, 16, 0, 0);
}

// ---------- convert x|skip concat -> bf16 [4096][2048] ----------
__global__ __launch_bounds__(256) void cvt_cat(const float* __restrict__ x,
                                               const float* __restrict__ skip,
                                               unsigned short* __restrict__ out) {
    const size_t i = ((size_t)blockIdx.x * 256 + threadIdx.x) * 8;
    const int r = (int)(i >> 11);
    const int c = (int)(i & 2047);
    const float* src = (c < 1024) ? (x + (size_t)r * 1024 + c)
                                  : (skip + (size_t)r * 1024 + (c - 1024));
    float4 v0 = *(const float4*)src;
    float4 v1 = *(const float4*)(src + 4);
    s16x8 o;
    o[0] = f2bf(v0.x); o[1] = f2bf(v0.y); o[2] = f2bf(v0.z); o[3] = f2bf(v0.w);
    o[4] = f2bf(v1.x); o[5] = f2bf(v1.y); o[6] = f2bf(v1.z); o[7] = f2bf(v1.w);
    *(s16x8*)(out + i) = o;
}

// ---------- fp32 [R][C] -> bf16 transpose [C][R] ----------
__global__ __launch_bounds__(256) void wt_tr(const float* __restrict__ in,
                                             unsigned short* __restrict__ out,
                                             int R, int C) {
    __shared__ unsigned short tile[64][72];
    const int nct = C >> 6;
    const int tr = blockIdx.x / nct, tc = blockIdx.x % nct;
    const int t = threadIdx.x;
    const int r = t >> 2, c0 = (t & 3) << 4;
    const float* src = in + (size_t)(tr * 64 + r) * C + tc * 64 + c0;
#pragma unroll
    for (int j = 0; j < 16; j += 4) {
        float4 v = *(const float4*)(src + j);
        tile[r][c0 + j]     = f2bf(v.x);
        tile[r][c0 + j + 1] = f2bf(v.y);
        tile[r][c0 + j + 2] = f2bf(v.z);
        tile[r][c0 + j + 3] = f2bf(v.w);
    }
    __syncthreads();
    const int oc = t >> 2, r0 = (t & 3) << 4;
    s16x8 o0, o1;
#pragma unroll
    for (int j = 0; j < 8; ++j) { o0[j] = tile[r0 + j][oc]; o1[j] = tile[r0 + 8 + j][oc]; }
    unsigned short* dst = out + (size_t)(tc * 64 + oc) * R + tr * 64 + r0;
    *(s16x8*)dst = o0;
    *(s16x8*)(dst + 8) = o1;
}

// ---------- V slice of qkv -> vt [B*H][64][1024] ----------
__global__ __launch_bounds__(256) void v_transpose(const unsigned short* __restrict__ qkv,
                                                   unsigned short* __restrict__ vt) {
    __shared__ unsigned short tile[64][72];
    const int bh = blockIdx.x >> 4, lt = blockIdx.x & 15;
    const int b = bh >> 4, h = bh & 15;
    const int t = threadIdx.x;
    const int r = t >> 2, c0 = (t & 3) << 4;
    const unsigned short* src =
        qkv + (size_t)(b * 1024 + lt * 64 + r) * 3072 + 2048 + h * 64 + c0;
    s16x8 v0 = *(const s16x8*)src;
    s16x8 v1 = *(const s16x8*)(src + 8);
#pragma unroll
    for (int j = 0; j < 8; ++j) { tile[r][c0 + j] = v0[j]; tile[r][c0 + 8 + j] = v1[j]; }
    __syncthreads();
    const int d = t >> 2, l0 = (t & 3) << 4;
    s16x8 o0, o1;
#pragma unroll
    for (int j = 0; j < 8; ++j) { o0[j] = tile[l0 + j][d]; o1[j] = tile[l0 + 8 + j][d]; }
    unsigned short* dst = vt + (size_t)bh * 65536 + (size_t)d * 1024 + lt * 64 + l0;
    *(s16x8*)dst = o0;
    *(s16x8*)(dst + 8) = o1;
}

// ---------- LayerNorm over rows of 1024, optional fp32 + bf16 outputs ----------
__global__ __launch_bounds__(256) void ln_kernel(const float* __restrict__ in,
                                                 const float* __restrict__ g,
                                                 const float* __restrict__ bb,
                                                 float* __restrict__ outf,
                                                 unsigned short* __restrict__ outb) {
    const int row = blockIdx.x;
    const int t = threadIdx.x;
    const float4 v = ((const float4*)(in + (size_t)row * 1024))[t];
    float s = v.x + v.y + v.z + v.w;
    float ss = v.x * v.x + v.y * v.y + v.z * v.z + v.w * v.w;
#pragma unroll
    for (int off = 1; off < 64; off <<= 1) {
        s += __shfl_xor(s, off, 64);
        ss += __shfl_xor(ss, off, 64);
    }
    __shared__ float red[8];
    const int wave = t >> 6, lane = t & 63;
    if (lane == 0) { red[wave] = s; red[4 + wave] = ss; }
    __syncthreads();
    s = red[0] + red[1] + red[2] + red[3];
    ss = red[4] + red[5] + red[6] + red[7];
    const float mean = s * 0.0009765625f;
    const float var = ss * 0.0009765625f - mean * mean;
    const float rstd = rsqrtf(var + 1e-5f);
    const float4 gv = ((const float4*)g)[t];
    const float4 bv = ((const float4*)bb)[t];
    float4 ov;
    ov.x = (v.x - mean) * rstd * gv.x + bv.x;
    ov.y = (v.y - mean) * rstd * gv.y + bv.y;
    ov.z = (v.z - mean) * rstd * gv.z + bv.z;
    ov.w = (v.w - mean) * rstd * gv.w + bv.w;
    if (outf) ((float4*)(outf + (size_t)row * 1024))[t] = ov;
    if (outb) {
        ushort4 ob;
        ob.x = f2bf(ov.x); ob.y = f2bf(ov.y); ob.z = f2bf(ov.z); ob.w = f2bf(ov.w);
        *(ushort4*)(outb + (size_t)row * 1024 + t * 4) = ob;
    }
}

// ---------- 128x128 GEMM (2-phase, vmcnt(0) via __syncthreads) ----------
// EPI 0: f32 out = acc + bias
// EPI 1: f32 out = acc + bias + resid
// EPI 2: bf16 out = acc            (no bias)
// EPI 3: bf16 out = gelu(acc+bias)
template <int EPI>
__global__ __launch_bounds__(256) void gemm_bt(const unsigned short* __restrict__ A,
                                               const unsigned short* __restrict__ Bt,
                                               void* __restrict__ outp,
                                               const float* __restrict__ bias,
                                               const float* __restrict__ resid,
                                               int M, int N, int K) {
    __shared__ __align__(16) unsigned short sA[2][128 * 32];
    __shared__ __align__(16) unsigned short sB[2][128 * 32];
    const int tid = threadIdx.x, wave = tid >> 6, lane = tid & 63;
    const int fr = lane & 15, fq = lane >> 4;
    const int nbn = N >> 7;
    // bijective XCD-chunked swizzle (gridDim.x % 8 == 0 for all call sites)
    const int wg = (blockIdx.x & 7) * ((int)gridDim.x >> 3) + (blockIdx.x >> 3);
    const int bm = wg / nbn, bn = wg % nbn;
    const int wm = wave >> 1, wn = wave & 1;
    const unsigned short* Ab = A + (size_t)bm * 128 * K;
    const unsigned short* Bb = Bt + (size_t)bn * 128 * K;
    const int srow = wave * 32 + (lane >> 2);
    const int scol = (lane & 3) * 8;

    f32x4 acc[4][4];
#pragma unroll
    for (int i = 0; i < 4; ++i)
#pragma unroll
        for (int j = 0; j < 4; ++j) acc[i][j] = (f32x4){0.f, 0.f, 0.f, 0.f};

    auto stage = [&](int buf, int k0) {
        const unsigned short* ga = Ab + (size_t)srow * K + k0 + scol;
        const unsigned short* gb = Bb + (size_t)srow * K + k0 + scol;
        unsigned short* la = &sA[buf][wave * 32 * 32];
        unsigned short* lb = &sB[buf][wave * 32 * 32];
        gload16(ga, la);
        gload16(ga + (size_t)16 * K, la + 16 * 32);
        gload16(gb, lb);
        gload16(gb + (size_t)16 * K, lb + 16 * 32);
    };

    const int nkt = K >> 5;
    stage(0, 0);
    for (int kt = 0; kt < nkt; ++kt) {
        __syncthreads();
        if (kt + 1 < nkt) stage((kt + 1) & 1, (kt + 1) * 32);
        const unsigned short* a0 = &sA[kt & 1][0];
        const unsigned short* b0 = &sB[kt & 1][0];
        s16x8 af[4], bf[4];
#pragma unroll
        for (int i = 0; i < 4; ++i)
            af[i] = *(const s16x8*)(a0 + (wm * 64 + i * 16 + fr) * 32 + fq * 8);
#pragma unroll
        for (int j = 0; j < 4; ++j)
            bf[j] = *(const s16x8*)(b0 + (wn * 64 + j * 16 + fr) * 32 + fq * 8);
#pragma unroll
        for (int i = 0; i < 4; ++i)
#pragma unroll
            for (int j = 0; j < 4; ++j) acc[i][j] = MFMA16(af[i], bf[j], acc[i][j]);
    }

#pragma unroll
    for (int i = 0; i < 4; ++i) {
        const int row0 = bm * 128 + wm * 64 + i * 16 + fq * 4;
#pragma unroll
        for (int j = 0; j < 4; ++j) {
            const int col = bn * 128 + wn * 64 + j * 16 + fr;
            const float bv = (EPI == 2) ? 0.f : bias[col];
#pragma unroll
            for (int r = 0; r < 4; ++r) {
                const int row = row0 + r;
                float v = acc[i][j][r] + bv;
                if (EPI == 3) v = fast_gelu(v);
                if (EPI == 1) v += resid[(size_t)row * N + col];
                if (EPI == 0 || EPI == 1)
                    ((float*)outp)[(size_t)row * N + col] = v;
                else
                    ((unsigned short*)outp)[(size_t)row * N + col] = f2bf(v);
            }
        }
    }
}

// ---------- 256x256 GEMM, 8 waves, quad-buffered BK=32, counted vmcnt ----------
// Raw s_barrier only (no vmcnt drain). Pipeline: prologue stages tiles 0,1,2;
// during tile t we stage tile t+3 into buf (t+3)&3. Top-of-tile wait:
// outstanding = tiles t+1,t+2 (4 gloads each per thread) -> vmcnt(8) keeps
// them in flight while guaranteeing tile t has landed (per-wave count; the
// following s_barrier extends the guarantee to all waves' shares).
// WAR safe: buf (t+3)&3 was last read in tile t-1, fully barrier-separated.
// EPI 2: bf16 out = acc ; EPI 3: bf16 out = gelu(acc+bias)
template <int EPI>
__global__ __launch_bounds__(512) void gemm256(const unsigned short* __restrict__ A,
                                               const unsigned short* __restrict__ Bt,
                                               unsigned short* __restrict__ outp,
                                               const float* __restrict__ bias,
                                               int N, int K) {
    __shared__ __align__(16) unsigned short lds[4][16384];  // 4 x (A 16KB | B 16KB)
    const int tid = threadIdx.x, wave = tid >> 6, lane = tid & 63;
    const int fr = lane & 15, fq = lane >> 4;
    const int wm = wave >> 2, wn = wave & 3;  // 2 x 4 wave grid
    const int nbn = N >> 8;
    const int wg = (blockIdx.x & 7) * ((int)gridDim.x >> 3) + (blockIdx.x >> 3);
    const int bm = wg / nbn, bn = wg % nbn;
    const unsigned short* Ab = A + (size_t)bm * 256 * K;
    const unsigned short* Bb = Bt + (size_t)bn * 256 * K;
    const int nt = K >> 5;

    f32x4 acc[8][4];
#pragma unroll
    for (int i = 0; i < 8; ++i)
#pragma unroll
        for (int n = 0; n < 4; ++n) acc[i][n] = (f32x4){0.f, 0.f, 0.f, 0.f};

    const int srow = tid >> 2;           // 0..127
    const int scol = (tid & 3) * 8;      // k-offset elems

    // stage sweeps s0, s0+1 of K-tile tt (s: 0=A rows0-127, 1=A rows128-255,
    // 2=B rows0-127, 3=B rows128-255); dest linear = buf + s*8KB + tid*16
    auto stage2 = [&](int tt, int s0) {
#pragma unroll
        for (int s = s0; s < s0 + 2; ++s) {
            const unsigned short* base = (s < 2) ? Ab : Bb;
            const int row = ((s & 1) << 7) + srow;
            gload16(base + (size_t)row * K + tt * 32 + scol,
                    (char*)&lds[tt & 3][0] + s * 8192 + tid * 16);
        }
    };

    stage2(0, 0); stage2(0, 2);
    stage2(1, 0); stage2(1, 2);
    stage2(2, 0); stage2(2, 2);

    for (int t = 0; t < nt; ++t) {
        __builtin_amdgcn_sched_barrier(0);
        if (t + 2 < nt)      asm volatile("s_waitcnt vmcnt(8)" ::: "memory");
        else if (t + 1 < nt) asm volatile("s_waitcnt vmcnt(4)" ::: "memory");
        else                 asm volatile("s_waitcnt vmcnt(0)" ::: "memory");
        __builtin_amdgcn_sched_barrier(0);
        __builtin_amdgcn_s_barrier();

        const unsigned short* lb = &lds[t & 3][0];
        s16x8 af[4], bfr[4];
        // ---- phase 0: rows wm*128 + 0..63 ----
#pragma unroll
        for (int i = 0; i < 4; ++i)
            af[i] = *(const s16x8*)(lb + (wm * 128 + i * 16 + fr) * 32 + fq * 8);
#pragma unroll
        for (int n = 0; n < 4; ++n)
            bfr[n] = *(const s16x8*)(lb + 8192 + (wn * 64 + n * 16 + fr) * 32 + fq * 8);
        if (t + 3 < nt) stage2(t + 3, 0);
        __builtin_amdgcn_s_barrier();
        __builtin_amdgcn_s_setprio(1);
#pragma unroll
        for (int i = 0; i < 4; ++i)
#pragma unroll
            for (int n = 0; n < 4; ++n) acc[i][n] = MFMA16(af[i], bfr[n], acc[i][n]);
        __builtin_amdgcn_s_setprio(0);
        __builtin_amdgcn_s_barrier();
        // ---- phase 1: rows wm*128 + 64..127 (B reused from regs) ----
#pragma unroll
        for (int i = 0; i < 4; ++i)
            af[i] = *(const s16x8*)(lb + (wm * 128 + 64 + i * 16 + fr) * 32 + fq * 8);
        if (t + 3 < nt) stage2(t + 3, 2);
        __builtin_amdgcn_s_barrier();
        __builtin_amdgcn_s_setprio(1);
#pragma unroll
        for (int i = 0; i < 4; ++i)
#pragma unroll
            for (int n = 0; n < 4; ++n) acc[4 + i][n] = MFMA16(af[i], bfr[n], acc[4 + i][n]);
        __builtin_amdgcn_s_setprio(0);
        __builtin_amdgcn_s_barrier();
    }

#pragma unroll
    for (int a2 = 0; a2 < 8; ++a2) {
        const int row0 = bm * 256 + wm * 128 + ((a2 >> 2) << 6) + ((a2 & 3) << 4) + fq * 4;
#pragma unroll
        for (int n = 0; n < 4; ++n) {
            const int col = bn * 256 + wn * 64 + n * 16 + fr;
            const float bv = (EPI == 3) ? bias[col] : 0.f;
#pragma unroll
            for (int r = 0; r < 4; ++r) {
                float v = acc[a2][n][r] + bv;
                if (EPI == 3) v = fast_gelu(v);
                outp[(size_t)(row0 + r) * N + col] = f2bf(v);
            }
        }
    }
}

// ---------- attention (flash, LDS-staged K/V, swizzled) ----------
__global__ __launch_bounds__(256) void attn_kernel(const unsigned short* __restrict__ qkv,
                                                   const unsigned short* __restrict__ vt,
                                                   unsigned short* __restrict__ o) {
    __shared__ __align__(16) unsigned short sK[2][64 * 64];
    __shared__ __align__(16) unsigned short sV[2][64 * 64];
    __shared__ __align__(16) unsigned short sP[4][16 * 64];

    const int j = blockIdx.x;
    const int xcd = j & 7, ix = j >> 3;
    const int bh = xcd * 8 + (ix >> 4);
    const int qt = ix & 15;
    const int b = bh >> 4, h = bh & 15;

    const int tid = threadIdx.x;
    const int wave = tid >> 6, lane = tid & 63;
    const int fr = lane & 15, fq = lane >> 4;

    const unsigned short* kbase = qkv + (size_t)(b * 1024) * 3072 + 1024 + h * 64;
    const unsigned short* vbase = vt + (size_t)bh * 65536;

    const int qrow0 = b * 1024 + qt * 64 + wave * 16;
    const unsigned short* qp = qkv + (size_t)(qrow0 + fr) * 3072 + h * 64;
    const s16x8 aq0 = *(const s16x8*)(qp + fq * 8);
    const s16x8 aq1 = *(const s16x8*)(qp + 32 + fq * 8);

    const f32x4 zero4 = {0.f, 0.f, 0.f, 0.f};
    float m[4], l[4];
    f32x4 oacc[4];
#pragma unroll
    for (int r = 0; r < 4; ++r) { m[r] = -1e30f; l[r] = 0.f; }
#pragma unroll
    for (int n = 0; n < 4; ++n) oacc[n] = zero4;

    auto stage = [&](int buf, int kt) {
#pragma unroll
        for (int c = 0; c < 2; ++c) {
            const int ob = tid * 16 + c * 4096;
            const int row = ob >> 7;
            const int slot = (ob >> 4) & 7;
            const int cole = ((slot ^ (row & 7)) << 3);
            gload16(kbase + (size_t)(kt * 64 + row) * 3072 + cole,
                    (char*)&sK[buf][0] + ob);
            gload16(vbase + (size_t)row * 1024 + kt * 64 + cole,
                    (char*)&sV[buf][0] + ob);
        }
    };

    unsigned short* pw = &sP[wave][0];
    const int psw = (fr & 7) << 4;

    stage(0, 0);
    for (int kt = 0; kt < 16; ++kt) {
        const int cur = kt & 1;
        __syncthreads();
        if (kt + 1 < 16) stage(cur ^ 1, kt + 1);

        const unsigned short* kb = &sK[cur][0];
        f32x4 s[4];
        __builtin_amdgcn_s_setprio(1);
#pragma unroll
        for (int n = 0; n < 4; ++n) {
            const int R = n * 16 + fr;
            const int sw = (R & 7) << 3;
            const s16x8 bk0 = *(const s16x8*)(kb + R * 64 + ((fq * 8) ^ sw));
            const s16x8 bk1 = *(const s16x8*)(kb + R * 64 + ((32 + fq * 8) ^ sw));
            s[n] = MFMA16(aq0, bk0, zero4);
            s[n] = MFMA16(aq1, bk1, s[n]);
        }
        __builtin_amdgcn_s_setprio(0);

        float mnew[4], alpha[4], rs[4];
#pragma unroll
        for (int r = 0; r < 4; ++r) {
            float t = fmaxf(fmaxf(s[0][r], s[1][r]), fmaxf(s[2][r], s[3][r])) * SCALE;
#pragma unroll
            for (int off = 1; off < 16; off <<= 1) t = fmaxf(t, __shfl_xor(t, off, 64));
            mnew[r] = fmaxf(m[r], t);
            alpha[r] = __expf(m[r] - mnew[r]);
            rs[r] = 0.f;
        }
#pragma unroll
        for (int n = 0; n < 4; ++n) {
#pragma unroll
            for (int r = 0; r < 4; ++r) {
                const float p = __expf(s[n][r] * SCALE - mnew[r]);
                rs[r] += p;
                const int prow = fq * 4 + r;
                const int pb = prow * 128 + (((n * 16 + fr) * 2) ^ ((prow & 7) << 4));
                *(unsigned short*)((char*)pw + pb) = f2bf(p);
            }
        }
#pragma unroll
        for (int r = 0; r < 4; ++r) {
            float t = rs[r];
#pragma unroll
            for (int off = 1; off < 16; off <<= 1) t += __shfl_xor(t, off, 64);
            l[r] = l[r] * alpha[r] + t;
            m[r] = mnew[r];
        }
#pragma unroll
        for (int n = 0; n < 4; ++n) {
            oacc[n][0] *= alpha[0]; oacc[n][1] *= alpha[1];
            oacc[n][2] *= alpha[2]; oacc[n][3] *= alpha[3];
        }

        const s16x8 ap0 = *(const s16x8*)((char*)pw + fr * 128 + ((fq * 16) ^ psw));
        const s16x8 ap1 = *(const s16x8*)((char*)pw + fr * 128 + ((64 + fq * 16) ^ psw));
        const unsigned short* vb = &sV[cur][0];
        __builtin_amdgcn_s_setprio(1);
#pragma unroll
        for (int n = 0; n < 4; ++n) {
            const int R = n * 16 + fr;
            const int sw = (R & 7) << 3;
            const s16x8 bv0 = *(const s16x8*)(vb + R * 64 + ((fq * 8) ^ sw));
            const s16x8 bv1 = *(const s16x8*)(vb + R * 64 + ((32 + fq * 8) ^ sw));
            oacc[n] = MFMA16(ap0, bv0, oacc[n]);
            oacc[n] = MFMA16(ap1, bv1, oacc[n]);
        }
        __builtin_amdgcn_s_setprio(0);
    }

#pragma unroll
    for (int r = 0; r < 4; ++r) {
        const float rl = 1.f / l[r];
        const int row = qrow0 + fq * 4 + r;
#pragma unroll
        for (int n = 0; n < 4; ++n) {
            const int col = h * 64 + n * 16 + fr;
            o[(size_t)row * 1024 + col] = f2bf(oacc[n][r] * rl);
        }
    }
}

// ---------- launcher ----------
extern "C" void kernel_launch(void* const* d_in, const int* in_sizes, int n_in,
                              void* d_out, int out_size, void* d_ws, size_t ws_size,
                              hipStream_t stream) {
    (void)in_sizes; (void)n_in; (void)out_size; (void)ws_size;
    const float* x      = (const float*)d_in[0];
    const float* skip   = (const float*)d_in[1];
    const float* skip_w = (const float*)d_in[2];
    const float* skip_b = (const float*)d_in[3];
    const float* ln1_g  = (const float*)d_in[4];
    const float* ln1_b  = (const float*)d_in[5];
    const float* qkv_w  = (const float*)d_in[6];
    const float* proj_w = (const float*)d_in[7];
    const float* proj_b = (const float*)d_in[8];
    const float* ln2_g  = (const float*)d_in[9];
    const float* ln2_b  = (const float*)d_in[10];
    const float* fc1_w  = (const float*)d_in[11];
    const float* fc1_b  = (const float*)d_in[12];
    const float* fc2_w  = (const float*)d_in[13];
    const float* fc2_b  = (const float*)d_in[14];
    const float* ln3_g  = (const float*)d_in[15];
    const float* ln3_b  = (const float*)d_in[16];

    char* ws = (char*)d_ws;
    const size_t MB = 1u << 20;
    unsigned short* skip_wT = (unsigned short*)(ws + 0 * MB);    // 4MB  [1024][2048]
    unsigned short* qkv_wT  = (unsigned short*)(ws + 4 * MB);    // 6MB  [3072][1024]
    unsigned short* proj_wT = (unsigned short*)(ws + 10 * MB);   // 2MB  [1024][1024]
    unsigned short* fc1_wT  = (unsigned short*)(ws + 12 * MB);   // 8MB  [4096][1024]
    unsigned short* fc2_wT  = (unsigned short*)(ws + 20 * MB);   // 8MB  [1024][4096]
    float* pre              = (float*)(ws + 28 * MB);            // 16MB [4096][1024] f32
    float* x1               = (float*)(ws + 44 * MB);            // 16MB
    unsigned short* x1b     = (unsigned short*)(ws + 60 * MB);   // 8MB
    unsigned short* qkvb    = (unsigned short*)(ws + 68 * MB);   // 24MB [4096][3072]
    float* x2n              = (float*)(ws + 68 * MB);            // aliases qkvb (dead by LN2)
    unsigned short* x2nb    = (unsigned short*)(ws + 84 * MB);   // 8MB (in old qkvb)
    unsigned short* vtb     = (unsigned short*)(ws + 92 * MB);   // 8MB [64][64][1024]
    unsigned short* ob      = (unsigned short*)(ws + 100 * MB);  // 8MB [4096][1024]
    unsigned short* hb      = (unsigned short*)(ws + 108 * MB);  // 32MB [4096][4096]
    unsigned short* xcatb   = (unsigned short*)(ws + 108 * MB);  // aliases hb (dead by fc1)
    float* outf = (float*)d_out;

    // weight conversions / transposes
    cvt_cat<<<4096, 256, 0, stream>>>(x, skip, xcatb);
    wt_tr<<<512, 256, 0, stream>>>(skip_w, skip_wT, 2048, 1024);
    wt_tr<<<768, 256, 0, stream>>>(qkv_w, qkv_wT, 1024, 3072);
    wt_tr<<<256, 256, 0, stream>>>(proj_w, proj_wT, 1024, 1024);
    wt_tr<<<1024, 256, 0, stream>>>(fc1_w, fc1_wT, 1024, 4096);
    wt_tr<<<1024, 256, 0, stream>>>(fc2_w, fc2_wT, 4096, 1024);

    // skip-cat GEMM -> pre ; LN1 -> x1 (f32) + x1b (bf16)
    gemm_bt<0><<<32 * 8, 256, 0, stream>>>(xcatb, skip_wT, pre, skip_b, nullptr, 4096, 1024, 2048);
    ln_kernel<<<4096, 256, 0, stream>>>(pre, ln1_g, ln1_b, x1, x1b);

    // qkv GEMM (bf16 out, no bias) — 256^2 pipelined
    gemm256<2><<<192, 512, 0, stream>>>(x1b, qkv_wT, qkvb, nullptr, 3072, 1024);

    // attention
    v_transpose<<<1024, 256, 0, stream>>>(qkvb, vtb);
    attn_kernel<<<1024, 256, 0, stream>>>(qkvb, vtb, ob);

    // proj GEMM + bias + residual(x1) -> pre ; LN2 -> x2n + x2nb
    gemm_bt<1><<<32 * 8, 256, 0, stream>>>(ob, proj_wT, pre, proj_b, x1, 4096, 1024, 1024);
    ln_kernel<<<4096, 256, 0, stream>>>(pre, ln2_g, ln2_b, x2n, x2nb);

    // fc1 GEMM + bias + GELU -> h (bf16) — 256^2 pipelined
    gemm256<3><<<256, 512, 0, stream>>>(x2nb, fc1_wT, hb, fc1_b, 4096, 1024);

    // fc2 GEMM + bias + residual(x2n) -> pre ; LN3 -> d_out (f32)
    gemm_bt<1><<<32 * 8, 256, 0, stream>>>(hb, fc2_wT, pre, fc2_b, x2n, 4096, 1024, 4096);
    ln_kernel<<<4096, 256, 0, stream>>>(pre, ln3_g, ln3_b, outf, nullptr);
}

// Round 5
// 433.397 us; speedup vs baseline: 1.3747x; 1.1340x over previous
//
#include <hip/hip_runtime.h>

// ---------- types / helpers ----------
typedef float f32x4 __attribute__((ext_vector_type(4)));
typedef short s16x8 __attribute__((ext_vector_type(8)));

#define MFMA16(a, b, c) __builtin_amdgcn_mfma_f32_16x16x32_bf16(a, b, c, 0, 0, 0)
#define SCALE 0.125f

__device__ __forceinline__ unsigned short f2bf(float f) {
    unsigned u = __float_as_uint(f);
    u = u + 0x7FFFu + ((u >> 16) & 1u);
    return (unsigned short)(u >> 16);
}

// clamped tanh-GELU via exp: gelu(x) ~= x * sigmoid(1.5957691(x + 0.044715 x^3))
__device__ __forceinline__ float fast_gelu(float x) {
    float u = 1.5957691216f * (x + 0.044715f * x * x * x);
    u = fminf(u, 30.f);                 // avoid inf/inf
    const float e = __expf(u);
    return x * e / (e + 1.f);
}

typedef const __attribute__((address_space(1))) void* gptr_t;
typedef __attribute__((address_space(3))) void* lptr_t;
__device__ __forceinline__ void gload16(const void* g, void* l) {
    __builtin_amdgcn_global_load_lds((gptr_t)g, (lptr_t)l, 16, 0, 0);
}

// ---------- convert x|skip concat -> bf16 [4096][2048] ----------
__global__ __launch_bounds__(256) void cvt_cat(const float* __restrict__ x,
                                               const float* __restrict__ skip,
                                               unsigned short* __restrict__ out) {
    const size_t i = ((size_t)blockIdx.x * 256 + threadIdx.x) * 8;
    const int r = (int)(i >> 11);
    const int c = (int)(i & 2047);
    const float* src = (c < 1024) ? (x + (size_t)r * 1024 + c)
                                  : (skip + (size_t)r * 1024 + (c - 1024));
    float4 v0 = *(const float4*)src;
    float4 v1 = *(const float4*)(src + 4);
    s16x8 o;
    o[0] = f2bf(v0.x); o[1] = f2bf(v0.y); o[2] = f2bf(v0.z); o[3] = f2bf(v0.w);
    o[4] = f2bf(v1.x); o[5] = f2bf(v1.y); o[6] = f2bf(v1.z); o[7] = f2bf(v1.w);
    *(s16x8*)(out + i) = o;
}

// ---------- fp32 [R][C] -> bf16 transpose [C][R] ----------
__global__ __launch_bounds__(256) void wt_tr(const float* __restrict__ in,
                                             unsigned short* __restrict__ out,
                                             int R, int C) {
    __shared__ unsigned short tile[64][72];
    const int nct = C >> 6;
    const int tr = blockIdx.x / nct, tc = blockIdx.x % nct;
    const int t = threadIdx.x;
    const int r = t >> 2, c0 = (t & 3) << 4;
    const float* src = in + (size_t)(tr * 64 + r) * C + tc * 64 + c0;
#pragma unroll
    for (int j = 0; j < 16; j += 4) {
        float4 v = *(const float4*)(src + j);
        tile[r][c0 + j]     = f2bf(v.x);
        tile[r][c0 + j + 1] = f2bf(v.y);
        tile[r][c0 + j + 2] = f2bf(v.z);
        tile[r][c0 + j + 3] = f2bf(v.w);
    }
    __syncthreads();
    const int oc = t >> 2, r0 = (t & 3) << 4;
    s16x8 o0, o1;
#pragma unroll
    for (int j = 0; j < 8; ++j) { o0[j] = tile[r0 + j][oc]; o1[j] = tile[r0 + 8 + j][oc]; }
    unsigned short* dst = out + (size_t)(tc * 64 + oc) * R + tr * 64 + r0;
    *(s16x8*)dst = o0;
    *(s16x8*)(dst + 8) = o1;
}

// ---------- V slice of qkv -> vt [B*H][64][1024] ----------
__global__ __launch_bounds__(256) void v_transpose(const unsigned short* __restrict__ qkv,
                                                   unsigned short* __restrict__ vt) {
    __shared__ unsigned short tile[64][72];
    const int bh = blockIdx.x >> 4, lt = blockIdx.x & 15;
    const int b = bh >> 4, h = bh & 15;
    const int t = threadIdx.x;
    const int r = t >> 2, c0 = (t & 3) << 4;
    const unsigned short* src =
        qkv + (size_t)(b * 1024 + lt * 64 + r) * 3072 + 2048 + h * 64 + c0;
    s16x8 v0 = *(const s16x8*)src;
    s16x8 v1 = *(const s16x8*)(src + 8);
#pragma unroll
    for (int j = 0; j < 8; ++j) { tile[r][c0 + j] = v0[j]; tile[r][c0 + 8 + j] = v1[j]; }
    __syncthreads();
    const int d = t >> 2, l0 = (t & 3) << 4;
    s16x8 o0, o1;
#pragma unroll
    for (int j = 0; j < 8; ++j) { o0[j] = tile[l0 + j][d]; o1[j] = tile[l0 + 8 + j][d]; }
    unsigned short* dst = vt + (size_t)bh * 65536 + (size_t)d * 1024 + lt * 64 + l0;
    *(s16x8*)dst = o0;
    *(s16x8*)(dst + 8) = o1;
}

// ---------- LayerNorm over rows of 1024, optional fp32 + bf16 outputs ----------
__global__ __launch_bounds__(256) void ln_kernel(const float* __restrict__ in,
                                                 const float* __restrict__ g,
                                                 const float* __restrict__ bb,
                                                 float* __restrict__ outf,
                                                 unsigned short* __restrict__ outb) {
    const int row = blockIdx.x;
    const int t = threadIdx.x;
    const float4 v = ((const float4*)(in + (size_t)row * 1024))[t];
    float s = v.x + v.y + v.z + v.w;
    float ss = v.x * v.x + v.y * v.y + v.z * v.z + v.w * v.w;
#pragma unroll
    for (int off = 1; off < 64; off <<= 1) {
        s += __shfl_xor(s, off, 64);
        ss += __shfl_xor(ss, off, 64);
    }
    __shared__ float red[8];
    const int wave = t >> 6, lane = t & 63;
    if (lane == 0) { red[wave] = s; red[4 + wave] = ss; }
    __syncthreads();
    s = red[0] + red[1] + red[2] + red[3];
    ss = red[4] + red[5] + red[6] + red[7];
    const float mean = s * 0.0009765625f;
    const float var = ss * 0.0009765625f - mean * mean;
    const float rstd = rsqrtf(var + 1e-5f);
    const float4 gv = ((const float4*)g)[t];
    const float4 bv = ((const float4*)bb)[t];
    float4 ov;
    ov.x = (v.x - mean) * rstd * gv.x + bv.x;
    ov.y = (v.y - mean) * rstd * gv.y + bv.y;
    ov.z = (v.z - mean) * rstd * gv.z + bv.z;
    ov.w = (v.w - mean) * rstd * gv.w + bv.w;
    if (outf) ((float4*)(outf + (size_t)row * 1024))[t] = ov;
    if (outb) {
        ushort4 ob;
        ob.x = f2bf(ov.x); ob.y = f2bf(ov.y); ob.z = f2bf(ov.z); ob.w = f2bf(ov.w);
        *(ushort4*)(outb + (size_t)row * 1024 + t * 4) = ob;
    }
}

// ---------- 128x128 GEMM, 4 waves, quad-buffered BK=32, counted vmcnt ----------
// One raw s_barrier per K-tile; vmcnt(8) keeps tiles t+1,t+2 in flight (4
// gloads/thread/tile). WAR: stage(t+3) writes buf (t-1)&3, whose reads
// completed before the top-of-t barrier (lgkmcnt before MFMA t-1 < barrier).
// LDS slot swizzle: source col ^= (row&3) slot, read XORs fq^(fr&3) (rule 21).
// EPI 0: f32 out = acc + bias ; EPI 1: f32 out = acc + bias + resid
template <int EPI>
__global__ __launch_bounds__(256) void gemm128p(const unsigned short* __restrict__ A,
                                                const unsigned short* __restrict__ Bt,
                                                float* __restrict__ outp,
                                                const float* __restrict__ bias,
                                                const float* __restrict__ resid,
                                                int N, int K) {
    __shared__ __align__(16) unsigned short lds[4][8192];  // buf: A 8KB | B 8KB
    const int tid = threadIdx.x, wave = tid >> 6, lane = tid & 63;
    const int fr = lane & 15, fq = lane >> 4;
    const int nbn = N >> 7;
    const int wg = (blockIdx.x & 7) * ((int)gridDim.x >> 3) + (blockIdx.x >> 3);
    const int bm = wg / nbn, bn = wg % nbn;
    const int wm = wave >> 1, wn = wave & 1;
    const unsigned short* Ab = A + (size_t)bm * 128 * K;
    const unsigned short* Bb = Bt + (size_t)bn * 128 * K;
    const int nt = K >> 5;

    f32x4 acc[4][4];
#pragma unroll
    for (int i = 0; i < 4; ++i)
#pragma unroll
        for (int j = 0; j < 4; ++j) acc[i][j] = (f32x4){0.f, 0.f, 0.f, 0.f};

    const int r0 = tid >> 2, slot = tid & 3;
    auto stage = [&](int tt) {
        char* dst = (char*)&lds[tt & 3][0];
#pragma unroll
        for (int h = 0; h < 2; ++h) {
            const int row = r0 + h * 64;
            const int cole = ((slot ^ (row & 3)) << 3);
            gload16(Ab + (size_t)row * K + tt * 32 + cole, dst + h * 4096 + tid * 16);
            gload16(Bb + (size_t)row * K + tt * 32 + cole, dst + 8192 + h * 4096 + tid * 16);
        }
    };

    stage(0); stage(1); stage(2);
    for (int t = 0; t < nt; ++t) {
        __builtin_amdgcn_sched_barrier(0);
        if (t + 2 < nt)      asm volatile("s_waitcnt vmcnt(8)" ::: "memory");
        else if (t + 1 < nt) asm volatile("s_waitcnt vmcnt(4)" ::: "memory");
        else                 asm volatile("s_waitcnt vmcnt(0)" ::: "memory");
        __builtin_amdgcn_sched_barrier(0);
        __builtin_amdgcn_s_barrier();

        const unsigned short* lb = &lds[t & 3][0];
        s16x8 af[4], bfr[4];
#pragma unroll
        for (int i = 0; i < 4; ++i)
            af[i] = *(const s16x8*)(lb + (wm * 64 + i * 16 + fr) * 32 + ((fq ^ (fr & 3)) << 3));
#pragma unroll
        for (int j = 0; j < 4; ++j)
            bfr[j] = *(const s16x8*)(lb + 4096 + (wn * 64 + j * 16 + fr) * 32 + ((fq ^ (fr & 3)) << 3));
        if (t + 3 < nt) stage(t + 3);
        __builtin_amdgcn_s_setprio(1);
#pragma unroll
        for (int i = 0; i < 4; ++i)
#pragma unroll
            for (int j = 0; j < 4; ++j) acc[i][j] = MFMA16(af[i], bfr[j], acc[i][j]);
        __builtin_amdgcn_s_setprio(0);
    }

#pragma unroll
    for (int i = 0; i < 4; ++i) {
        const int row0 = bm * 128 + wm * 64 + i * 16 + fq * 4;
#pragma unroll
        for (int j = 0; j < 4; ++j) {
            const int col = bn * 128 + wn * 64 + j * 16 + fr;
            const float bv = bias[col];
#pragma unroll
            for (int r = 0; r < 4; ++r) {
                const int row = row0 + r;
                float v = acc[i][j][r] + bv;
                if (EPI == 1) v += resid[(size_t)row * N + col];
                outp[(size_t)row * N + col] = v;
            }
        }
    }
}

// ---------- 256x256 GEMM, 8 waves, quad-buffered BK=32, counted vmcnt ----------
// EPI 2: bf16 out = acc ; EPI 3: bf16 out = gelu(acc+bias)
template <int EPI>
__global__ __launch_bounds__(512) void gemm256(const unsigned short* __restrict__ A,
                                               const unsigned short* __restrict__ Bt,
                                               unsigned short* __restrict__ outp,
                                               const float* __restrict__ bias,
                                               int N, int K) {
    __shared__ __align__(16) unsigned short lds[4][16384];  // 4 x (A 16KB | B 16KB)
    const int tid = threadIdx.x, wave = tid >> 6, lane = tid & 63;
    const int fr = lane & 15, fq = lane >> 4;
    const int wm = wave >> 2, wn = wave & 3;  // 2 x 4 wave grid
    const int nbn = N >> 8;
    const int wg = (blockIdx.x & 7) * ((int)gridDim.x >> 3) + (blockIdx.x >> 3);
    const int bm = wg / nbn, bn = wg % nbn;
    const unsigned short* Ab = A + (size_t)bm * 256 * K;
    const unsigned short* Bb = Bt + (size_t)bn * 256 * K;
    const int nt = K >> 5;

    f32x4 acc[8][4];
#pragma unroll
    for (int i = 0; i < 8; ++i)
#pragma unroll
        for (int n = 0; n < 4; ++n) acc[i][n] = (f32x4){0.f, 0.f, 0.f, 0.f};

    const int srow = tid >> 2;           // 0..127
    const int scole = (((tid & 3) ^ (srow & 3)) << 3);  // pre-swizzled source col

    auto stage2 = [&](int tt, int s0) {
#pragma unroll
        for (int s = s0; s < s0 + 2; ++s) {
            const unsigned short* base = (s < 2) ? Ab : Bb;
            const int row = ((s & 1) << 7) + srow;
            gload16(base + (size_t)row * K + tt * 32 + scole,
                    (char*)&lds[tt & 3][0] + s * 8192 + tid * 16);
        }
    };

    stage2(0, 0); stage2(0, 2);
    stage2(1, 0); stage2(1, 2);
    stage2(2, 0); stage2(2, 2);

    for (int t = 0; t < nt; ++t) {
        __builtin_amdgcn_sched_barrier(0);
        if (t + 2 < nt)      asm volatile("s_waitcnt vmcnt(8)" ::: "memory");
        else if (t + 1 < nt) asm volatile("s_waitcnt vmcnt(4)" ::: "memory");
        else                 asm volatile("s_waitcnt vmcnt(0)" ::: "memory");
        __builtin_amdgcn_sched_barrier(0);
        __builtin_amdgcn_s_barrier();

        const unsigned short* lb = &lds[t & 3][0];
        s16x8 af[4], bfr[4];
        const int rsw = (fq ^ (fr & 3)) << 3;
        // ---- phase 0: rows wm*128 + 0..63 ----
#pragma unroll
        for (int i = 0; i < 4; ++i)
            af[i] = *(const s16x8*)(lb + (wm * 128 + i * 16 + fr) * 32 + rsw);
#pragma unroll
        for (int n = 0; n < 4; ++n)
            bfr[n] = *(const s16x8*)(lb + 8192 + (wn * 64 + n * 16 + fr) * 32 + rsw);
        if (t + 3 < nt) stage2(t + 3, 0);
        __builtin_amdgcn_s_barrier();
        __builtin_amdgcn_s_setprio(1);
#pragma unroll
        for (int i = 0; i < 4; ++i)
#pragma unroll
            for (int n = 0; n < 4; ++n) acc[i][n] = MFMA16(af[i], bfr[n], acc[i][n]);
        __builtin_amdgcn_s_setprio(0);
        __builtin_amdgcn_s_barrier();
        // ---- phase 1: rows wm*128 + 64..127 (B reused from regs) ----
#pragma unroll
        for (int i = 0; i < 4; ++i)
            af[i] = *(const s16x8*)(lb + (wm * 128 + 64 + i * 16 + fr) * 32 + rsw);
        if (t + 3 < nt) stage2(t + 3, 2);
        __builtin_amdgcn_s_barrier();
        __builtin_amdgcn_s_setprio(1);
#pragma unroll
        for (int i = 0; i < 4; ++i)
#pragma unroll
            for (int n = 0; n < 4; ++n) acc[4 + i][n] = MFMA16(af[i], bfr[n], acc[4 + i][n]);
        __builtin_amdgcn_s_setprio(0);
        __builtin_amdgcn_s_barrier();
    }

#pragma unroll
    for (int a2 = 0; a2 < 8; ++a2) {
        const int row0 = bm * 256 + wm * 128 + ((a2 >> 2) << 6) + ((a2 & 3) << 4) + fq * 4;
#pragma unroll
        for (int n = 0; n < 4; ++n) {
            const int col = bn * 256 + wn * 64 + n * 16 + fr;
            const float bv = (EPI == 3) ? bias[col] : 0.f;
#pragma unroll
            for (int r = 0; r < 4; ++r) {
                float v = acc[a2][n][r] + bv;
                if (EPI == 3) v = fast_gelu(v);
                outp[(size_t)(row0 + r) * N + col] = f2bf(v);
            }
        }
    }
}

// ---------- attention (flash, LDS-staged K/V, swizzled) ----------
__global__ __launch_bounds__(256) void attn_kernel(const unsigned short* __restrict__ qkv,
                                                   const unsigned short* __restrict__ vt,
                                                   unsigned short* __restrict__ o) {
    __shared__ __align__(16) unsigned short sK[2][64 * 64];
    __shared__ __align__(16) unsigned short sV[2][64 * 64];
    __shared__ __align__(16) unsigned short sP[4][16 * 64];

    const int j = blockIdx.x;
    const int xcd = j & 7, ix = j >> 3;
    const int bh = xcd * 8 + (ix >> 4);
    const int qt = ix & 15;
    const int b = bh >> 4, h = bh & 15;

    const int tid = threadIdx.x;
    const int wave = tid >> 6, lane = tid & 63;
    const int fr = lane & 15, fq = lane >> 4;

    const unsigned short* kbase = qkv + (size_t)(b * 1024) * 3072 + 1024 + h * 64;
    const unsigned short* vbase = vt + (size_t)bh * 65536;

    const int qrow0 = b * 1024 + qt * 64 + wave * 16;
    const unsigned short* qp = qkv + (size_t)(qrow0 + fr) * 3072 + h * 64;
    const s16x8 aq0 = *(const s16x8*)(qp + fq * 8);
    const s16x8 aq1 = *(const s16x8*)(qp + 32 + fq * 8);

    const f32x4 zero4 = {0.f, 0.f, 0.f, 0.f};
    float m[4], l[4];
    f32x4 oacc[4];
#pragma unroll
    for (int r = 0; r < 4; ++r) { m[r] = -1e30f; l[r] = 0.f; }
#pragma unroll
    for (int n = 0; n < 4; ++n) oacc[n] = zero4;

    auto stage = [&](int buf, int kt) {
#pragma unroll
        for (int c = 0; c < 2; ++c) {
            const int ob = tid * 16 + c * 4096;
            const int row = ob >> 7;
            const int slot = (ob >> 4) & 7;
            const int cole = ((slot ^ (row & 7)) << 3);
            gload16(kbase + (size_t)(kt * 64 + row) * 3072 + cole,
                    (char*)&sK[buf][0] + ob);
            gload16(vbase + (size_t)row * 1024 + kt * 64 + cole,
                    (char*)&sV[buf][0] + ob);
        }
    };

    unsigned short* pw = &sP[wave][0];
    const int psw = (fr & 7) << 4;

    stage(0, 0);
    for (int kt = 0; kt < 16; ++kt) {
        const int cur = kt & 1;
        __syncthreads();
        if (kt + 1 < 16) stage(cur ^ 1, kt + 1);

        const unsigned short* kb = &sK[cur][0];
        f32x4 s[4];
        __builtin_amdgcn_s_setprio(1);
#pragma unroll
        for (int n = 0; n < 4; ++n) {
            const int R = n * 16 + fr;
            const int sw = (R & 7) << 3;
            const s16x8 bk0 = *(const s16x8*)(kb + R * 64 + ((fq * 8) ^ sw));
            const s16x8 bk1 = *(const s16x8*)(kb + R * 64 + ((32 + fq * 8) ^ sw));
            s[n] = MFMA16(aq0, bk0, zero4);
            s[n] = MFMA16(aq1, bk1, s[n]);
        }
        __builtin_amdgcn_s_setprio(0);

        float mnew[4], alpha[4], rs[4];
#pragma unroll
        for (int r = 0; r < 4; ++r) {
            float t = fmaxf(fmaxf(s[0][r], s[1][r]), fmaxf(s[2][r], s[3][r])) * SCALE;
#pragma unroll
            for (int off = 1; off < 16; off <<= 1) t = fmaxf(t, __shfl_xor(t, off, 64));
            mnew[r] = fmaxf(m[r], t);
            alpha[r] = __expf(m[r] - mnew[r]);
            rs[r] = 0.f;
        }
#pragma unroll
        for (int n = 0; n < 4; ++n) {
#pragma unroll
            for (int r = 0; r < 4; ++r) {
                const float p = __expf(s[n][r] * SCALE - mnew[r]);
                rs[r] += p;
                const int prow = fq * 4 + r;
                const int pb = prow * 128 + (((n * 16 + fr) * 2) ^ ((prow & 7) << 4));
                *(unsigned short*)((char*)pw + pb) = f2bf(p);
            }
        }
#pragma unroll
        for (int r = 0; r < 4; ++r) {
            float t = rs[r];
#pragma unroll
            for (int off = 1; off < 16; off <<= 1) t += __shfl_xor(t, off, 64);
            l[r] = l[r] * alpha[r] + t;
            m[r] = mnew[r];
        }
#pragma unroll
        for (int n = 0; n < 4; ++n) {
            oacc[n][0] *= alpha[0]; oacc[n][1] *= alpha[1];
            oacc[n][2] *= alpha[2]; oacc[n][3] *= alpha[3];
        }

        const s16x8 ap0 = *(const s16x8*)((char*)pw + fr * 128 + ((fq * 16) ^ psw));
        const s16x8 ap1 = *(const s16x8*)((char*)pw + fr * 128 + ((64 + fq * 16) ^ psw));
        const unsigned short* vb = &sV[cur][0];
        __builtin_amdgcn_s_setprio(1);
#pragma unroll
        for (int n = 0; n < 4; ++n) {
            const int R = n * 16 + fr;
            const int sw = (R & 7) << 3;
            const s16x8 bv0 = *(const s16x8*)(vb + R * 64 + ((fq * 8) ^ sw));
            const s16x8 bv1 = *(const s16x8*)(vb + R * 64 + ((32 + fq * 8) ^ sw));
            oacc[n] = MFMA16(ap0, bv0, oacc[n]);
            oacc[n] = MFMA16(ap1, bv1, oacc[n]);
        }
        __builtin_amdgcn_s_setprio(0);
    }

#pragma unroll
    for (int r = 0; r < 4; ++r) {
        const float rl = 1.f / l[r];
        const int row = qrow0 + fq * 4 + r;
#pragma unroll
        for (int n = 0; n < 4; ++n) {
            const int col = h * 64 + n * 16 + fr;
            o[(size_t)row * 1024 + col] = f2bf(oacc[n][r] * rl);
        }
    }
}

// ---------- launcher ----------
extern "C" void kernel_launch(void* const* d_in, const int* in_sizes, int n_in,
                              void* d_out, int out_size, void* d_ws, size_t ws_size,
                              hipStream_t stream) {
    (void)in_sizes; (void)n_in; (void)out_size; (void)ws_size;
    const float* x      = (const float*)d_in[0];
    const float* skip   = (const float*)d_in[1];
    const float* skip_w = (const float*)d_in[2];
    const float* skip_b = (const float*)d_in[3];
    const float* ln1_g  = (const float*)d_in[4];
    const float* ln1_b  = (const float*)d_in[5];
    const float* qkv_w  = (const float*)d_in[6];
    const float* proj_w = (const float*)d_in[7];
    const float* proj_b = (const float*)d_in[8];
    const float* ln2_g  = (const float*)d_in[9];
    const float* ln2_b  = (const float*)d_in[10];
    const float* fc1_w  = (const float*)d_in[11];
    const float* fc1_b  = (const float*)d_in[12];
    const float* fc2_w  = (const float*)d_in[13];
    const float* fc2_b  = (const float*)d_in[14];
    const float* ln3_g  = (const float*)d_in[15];
    const float* ln3_b  = (const float*)d_in[16];

    char* ws = (char*)d_ws;
    const size_t MB = 1u << 20;
    unsigned short* skip_wT = (unsigned short*)(ws + 0 * MB);    // 4MB  [1024][2048]
    unsigned short* qkv_wT  = (unsigned short*)(ws + 4 * MB);    // 6MB  [3072][1024]
    unsigned short* proj_wT = (unsigned short*)(ws + 10 * MB);   // 2MB  [1024][1024]
    unsigned short* fc1_wT  = (unsigned short*)(ws + 12 * MB);   // 8MB  [4096][1024]
    unsigned short* fc2_wT  = (unsigned short*)(ws + 20 * MB);   // 8MB  [1024][4096]
    float* pre              = (float*)(ws + 28 * MB);            // 16MB [4096][1024] f32
    float* x1               = (float*)(ws + 44 * MB);            // 16MB
    unsigned short* x1b     = (unsigned short*)(ws + 60 * MB);   // 8MB
    unsigned short* qkvb    = (unsigned short*)(ws + 68 * MB);   // 24MB [4096][3072]
    float* x2n              = (float*)(ws + 68 * MB);            // aliases qkvb (dead by LN2)
    unsigned short* x2nb    = (unsigned short*)(ws + 84 * MB);   // 8MB (in old qkvb)
    unsigned short* vtb     = (unsigned short*)(ws + 92 * MB);   // 8MB [64][64][1024]
    unsigned short* ob      = (unsigned short*)(ws + 100 * MB);  // 8MB [4096][1024]
    unsigned short* hb      = (unsigned short*)(ws + 108 * MB);  // 32MB [4096][4096]
    unsigned short* xcatb   = (unsigned short*)(ws + 108 * MB);  // aliases hb (dead by fc1)
    float* outf = (float*)d_out;

    // weight conversions / transposes
    cvt_cat<<<4096, 256, 0, stream>>>(x, skip, xcatb);
    wt_tr<<<512, 256, 0, stream>>>(skip_w, skip_wT, 2048, 1024);
    wt_tr<<<768, 256, 0, stream>>>(qkv_w, qkv_wT, 1024, 3072);
    wt_tr<<<256, 256, 0, stream>>>(proj_w, proj_wT, 1024, 1024);
    wt_tr<<<1024, 256, 0, stream>>>(fc1_w, fc1_wT, 1024, 4096);
    wt_tr<<<1024, 256, 0, stream>>>(fc2_w, fc2_wT, 4096, 1024);

    // skip-cat GEMM -> pre ; LN1 -> x1 (f32) + x1b (bf16)
    gemm128p<0><<<256, 256, 0, stream>>>(xcatb, skip_wT, pre, skip_b, nullptr, 1024, 2048);
    ln_kernel<<<4096, 256, 0, stream>>>(pre, ln1_g, ln1_b, x1, x1b);

    // qkv GEMM (bf16 out, no bias) — 256^2 pipelined
    gemm256<2><<<192, 512, 0, stream>>>(x1b, qkv_wT, qkvb, nullptr, 3072, 1024);

    // attention
    v_transpose<<<1024, 256, 0, stream>>>(qkvb, vtb);
    attn_kernel<<<1024, 256, 0, stream>>>(qkvb, vtb, ob);

    // proj GEMM + bias + residual(x1) -> pre ; LN2 -> x2n + x2nb
    gemm128p<1><<<256, 256, 0, stream>>>(ob, proj_wT, pre, proj_b, x1, 1024, 1024);
    ln_kernel<<<4096, 256, 0, stream>>>(pre, ln2_g, ln2_b, x2n, x2nb);

    // fc1 GEMM + bias + GELU -> h (bf16) — 256^2 pipelined
    gemm256<3><<<256, 512, 0, stream>>>(x2nb, fc1_wT, hb, fc1_b, 4096, 1024);

    // fc2 GEMM + bias + residual(x2n) -> pre ; LN3 -> d_out (f32)
    gemm128p<1><<<256, 256, 0, stream>>>(hb, fc2_wT, pre, fc2_b, x2n, 1024, 4096);
    ln_kernel<<<4096, 256, 0, stream>>>(pre, ln3_g, ln3_b, outf, nullptr);
}

// Round 6
// 409.915 us; speedup vs baseline: 1.4534x; 1.0573x over previous
//
#include <hip/hip_runtime.h>

// ---------- types / helpers ----------
typedef float f32x4 __attribute__((ext_vector_type(4)));
typedef short s16x8 __attribute__((ext_vector_type(8)));

#define MFMA16(a, b, c) __builtin_amdgcn_mfma_f32_16x16x32_bf16(a, b, c, 0, 0, 0)
#define SCALE 0.125f

__device__ __forceinline__ unsigned short f2bf(float f) {
    unsigned u = __float_as_uint(f);
    u = u + 0x7FFFu + ((u >> 16) & 1u);
    return (unsigned short)(u >> 16);
}

// clamped tanh-GELU via exp: gelu(x) ~= x * sigmoid(1.5957691(x + 0.044715 x^3))
__device__ __forceinline__ float fast_gelu(float x) {
    float u = 1.5957691216f * (x + 0.044715f * x * x * x);
    u = fminf(u, 30.f);                 // avoid inf/inf
    const float e = __expf(u);
    return x * e / (e + 1.f);
}

typedef const __attribute__((address_space(1))) void* gptr_t;
typedef __attribute__((address_space(3))) void* lptr_t;
__device__ __forceinline__ void gload16(const void* g, void* l) {
    __builtin_amdgcn_global_load_lds((gptr_t)g, (lptr_t)l, 16, 0, 0);
}

// ---------- convert x|skip concat -> bf16 [4096][2048] ----------
__global__ __launch_bounds__(256) void cvt_cat(const float* __restrict__ x,
                                               const float* __restrict__ skip,
                                               unsigned short* __restrict__ out) {
    const size_t i = ((size_t)blockIdx.x * 256 + threadIdx.x) * 8;
    const int r = (int)(i >> 11);
    const int c = (int)(i & 2047);
    const float* src = (c < 1024) ? (x + (size_t)r * 1024 + c)
                                  : (skip + (size_t)r * 1024 + (c - 1024));
    float4 v0 = *(const float4*)src;
    float4 v1 = *(const float4*)(src + 4);
    s16x8 o;
    o[0] = f2bf(v0.x); o[1] = f2bf(v0.y); o[2] = f2bf(v0.z); o[3] = f2bf(v0.w);
    o[4] = f2bf(v1.x); o[5] = f2bf(v1.y); o[6] = f2bf(v1.z); o[7] = f2bf(v1.w);
    *(s16x8*)(out + i) = o;
}

// ---------- fp32 [R][C] -> bf16 transpose [C][R] ----------
__global__ __launch_bounds__(256) void wt_tr(const float* __restrict__ in,
                                             unsigned short* __restrict__ out,
                                             int R, int C) {
    __shared__ unsigned short tile[64][72];
    const int nct = C >> 6;
    const int tr = blockIdx.x / nct, tc = blockIdx.x % nct;
    const int t = threadIdx.x;
    const int r = t >> 2, c0 = (t & 3) << 4;
    const float* src = in + (size_t)(tr * 64 + r) * C + tc * 64 + c0;
#pragma unroll
    for (int j = 0; j < 16; j += 4) {
        float4 v = *(const float4*)(src + j);
        tile[r][c0 + j]     = f2bf(v.x);
        tile[r][c0 + j + 1] = f2bf(v.y);
        tile[r][c0 + j + 2] = f2bf(v.z);
        tile[r][c0 + j + 3] = f2bf(v.w);
    }
    __syncthreads();
    const int oc = t >> 2, r0 = (t & 3) << 4;
    s16x8 o0, o1;
#pragma unroll
    for (int j = 0; j < 8; ++j) { o0[j] = tile[r0 + j][oc]; o1[j] = tile[r0 + 8 + j][oc]; }
    unsigned short* dst = out + (size_t)(tc * 64 + oc) * R + tr * 64 + r0;
    *(s16x8*)dst = o0;
    *(s16x8*)(dst + 8) = o1;
}

// ---------- V slice of qkv -> vt [B*H][64][1024] ----------
__global__ __launch_bounds__(256) void v_transpose(const unsigned short* __restrict__ qkv,
                                                   unsigned short* __restrict__ vt) {
    __shared__ unsigned short tile[64][72];
    const int bh = blockIdx.x >> 4, lt = blockIdx.x & 15;
    const int b = bh >> 4, h = bh & 15;
    const int t = threadIdx.x;
    const int r = t >> 2, c0 = (t & 3) << 4;
    const unsigned short* src =
        qkv + (size_t)(b * 1024 + lt * 64 + r) * 3072 + 2048 + h * 64 + c0;
    s16x8 v0 = *(const s16x8*)src;
    s16x8 v1 = *(const s16x8*)(src + 8);
#pragma unroll
    for (int j = 0; j < 8; ++j) { tile[r][c0 + j] = v0[j]; tile[r][c0 + 8 + j] = v1[j]; }
    __syncthreads();
    const int d = t >> 2, l0 = (t & 3) << 4;
    s16x8 o0, o1;
#pragma unroll
    for (int j = 0; j < 8; ++j) { o0[j] = tile[l0 + j][d]; o1[j] = tile[l0 + 8 + j][d]; }
    unsigned short* dst = vt + (size_t)bh * 65536 + (size_t)d * 1024 + lt * 64 + l0;
    *(s16x8*)dst = o0;
    *(s16x8*)(dst + 8) = o1;
}

// ---------- LayerNorm over rows of 1024, optional fp32 + bf16 outputs ----------
__global__ __launch_bounds__(256) void ln_kernel(const float* __restrict__ in,
                                                 const float* __restrict__ g,
                                                 const float* __restrict__ bb,
                                                 float* __restrict__ outf,
                                                 unsigned short* __restrict__ outb) {
    const int row = blockIdx.x;
    const int t = threadIdx.x;
    const float4 v = ((const float4*)(in + (size_t)row * 1024))[t];
    float s = v.x + v.y + v.z + v.w;
    float ss = v.x * v.x + v.y * v.y + v.z * v.z + v.w * v.w;
#pragma unroll
    for (int off = 1; off < 64; off <<= 1) {
        s += __shfl_xor(s, off, 64);
        ss += __shfl_xor(ss, off, 64);
    }
    __shared__ float red[8];
    const int wave = t >> 6, lane = t & 63;
    if (lane == 0) { red[wave] = s; red[4 + wave] = ss; }
    __syncthreads();
    s = red[0] + red[1] + red[2] + red[3];
    ss = red[4] + red[5] + red[6] + red[7];
    const float mean = s * 0.0009765625f;
    const float var = ss * 0.0009765625f - mean * mean;
    const float rstd = rsqrtf(var + 1e-5f);
    const float4 gv = ((const float4*)g)[t];
    const float4 bv = ((const float4*)bb)[t];
    float4 ov;
    ov.x = (v.x - mean) * rstd * gv.x + bv.x;
    ov.y = (v.y - mean) * rstd * gv.y + bv.y;
    ov.z = (v.z - mean) * rstd * gv.z + bv.z;
    ov.w = (v.w - mean) * rstd * gv.w + bv.w;
    if (outf) ((float4*)(outf + (size_t)row * 1024))[t] = ov;
    if (outb) {
        ushort4 ob;
        ob.x = f2bf(ov.x); ob.y = f2bf(ov.y); ob.z = f2bf(ov.z); ob.w = f2bf(ov.w);
        *(ushort4*)(outb + (size_t)row * 1024 + t * 4) = ob;
    }
}

// ---------- 128x128 GEMM, 4 waves, quad-buffered BK=32, counted vmcnt ----------
// EPI 0: f32 out = acc + bias ; EPI 1: f32 out = acc + bias + resid
template <int EPI>
__global__ __launch_bounds__(256) void gemm128p(const unsigned short* __restrict__ A,
                                                const unsigned short* __restrict__ Bt,
                                                float* __restrict__ outp,
                                                const float* __restrict__ bias,
                                                const float* __restrict__ resid,
                                                int N, int K) {
    __shared__ __align__(16) unsigned short lds[4][8192];  // buf: A 8KB | B 8KB
    const int tid = threadIdx.x, wave = tid >> 6, lane = tid & 63;
    const int fr = lane & 15, fq = lane >> 4;
    const int nbn = N >> 7;
    const int wg = (blockIdx.x & 7) * ((int)gridDim.x >> 3) + (blockIdx.x >> 3);
    const int bm = wg / nbn, bn = wg % nbn;
    const int wm = wave >> 1, wn = wave & 1;
    const unsigned short* Ab = A + (size_t)bm * 128 * K;
    const unsigned short* Bb = Bt + (size_t)bn * 128 * K;
    const int nt = K >> 5;

    f32x4 acc[4][4];
#pragma unroll
    for (int i = 0; i < 4; ++i)
#pragma unroll
        for (int j = 0; j < 4; ++j) acc[i][j] = (f32x4){0.f, 0.f, 0.f, 0.f};

    const int r0 = tid >> 2, slot = tid & 3;
    auto stage = [&](int tt) {
        char* dst = (char*)&lds[tt & 3][0];
#pragma unroll
        for (int h = 0; h < 2; ++h) {
            const int row = r0 + h * 64;
            const int cole = ((slot ^ (row & 3)) << 3);
            gload16(Ab + (size_t)row * K + tt * 32 + cole, dst + h * 4096 + tid * 16);
            gload16(Bb + (size_t)row * K + tt * 32 + cole, dst + 8192 + h * 4096 + tid * 16);
        }
    };

    stage(0); stage(1); stage(2);
    for (int t = 0; t < nt; ++t) {
        __builtin_amdgcn_sched_barrier(0);
        if (t + 2 < nt)      asm volatile("s_waitcnt vmcnt(8)" ::: "memory");
        else if (t + 1 < nt) asm volatile("s_waitcnt vmcnt(4)" ::: "memory");
        else                 asm volatile("s_waitcnt vmcnt(0)" ::: "memory");
        __builtin_amdgcn_sched_barrier(0);
        __builtin_amdgcn_s_barrier();

        const unsigned short* lb = &lds[t & 3][0];
        s16x8 af[4], bfr[4];
#pragma unroll
        for (int i = 0; i < 4; ++i)
            af[i] = *(const s16x8*)(lb + (wm * 64 + i * 16 + fr) * 32 + ((fq ^ (fr & 3)) << 3));
#pragma unroll
        for (int j = 0; j < 4; ++j)
            bfr[j] = *(const s16x8*)(lb + 4096 + (wn * 64 + j * 16 + fr) * 32 + ((fq ^ (fr & 3)) << 3));
        if (t + 3 < nt) stage(t + 3);
        __builtin_amdgcn_s_setprio(1);
#pragma unroll
        for (int i = 0; i < 4; ++i)
#pragma unroll
            for (int j = 0; j < 4; ++j) acc[i][j] = MFMA16(af[i], bfr[j], acc[i][j]);
        __builtin_amdgcn_s_setprio(0);
    }

#pragma unroll
    for (int i = 0; i < 4; ++i) {
        const int row0 = bm * 128 + wm * 64 + i * 16 + fq * 4;
#pragma unroll
        for (int j = 0; j < 4; ++j) {
            const int col = bn * 128 + wn * 64 + j * 16 + fr;
            const float bv = bias[col];
#pragma unroll
            for (int r = 0; r < 4; ++r) {
                const int row = row0 + r;
                float v = acc[i][j][r] + bv;
                if (EPI == 1) v += resid[(size_t)row * N + col];
                outp[(size_t)row * N + col] = v;
            }
        }
    }
}

// ---------- 256x256 GEMM, 8 waves, quad-buffered BK=32, counted vmcnt ----------
// EPI 2: bf16 out = acc ; EPI 3: bf16 out = gelu(acc+bias)
template <int EPI>
__global__ __launch_bounds__(512) void gemm256(const unsigned short* __restrict__ A,
                                               const unsigned short* __restrict__ Bt,
                                               unsigned short* __restrict__ outp,
                                               const float* __restrict__ bias,
                                               int N, int K) {
    __shared__ __align__(16) unsigned short lds[4][16384];  // 4 x (A 16KB | B 16KB)
    const int tid = threadIdx.x, wave = tid >> 6, lane = tid & 63;
    const int fr = lane & 15, fq = lane >> 4;
    const int wm = wave >> 2, wn = wave & 3;  // 2 x 4 wave grid
    const int nbn = N >> 8;
    const int wg = (blockIdx.x & 7) * ((int)gridDim.x >> 3) + (blockIdx.x >> 3);
    const int bm = wg / nbn, bn = wg % nbn;
    const unsigned short* Ab = A + (size_t)bm * 256 * K;
    const unsigned short* Bb = Bt + (size_t)bn * 256 * K;
    const int nt = K >> 5;

    f32x4 acc[8][4];
#pragma unroll
    for (int i = 0; i < 8; ++i)
#pragma unroll
        for (int n = 0; n < 4; ++n) acc[i][n] = (f32x4){0.f, 0.f, 0.f, 0.f};

    const int srow = tid >> 2;           // 0..127
    const int scole = (((tid & 3) ^ (srow & 3)) << 3);  // pre-swizzled source col

    auto stage2 = [&](int tt, int s0) {
#pragma unroll
        for (int s = s0; s < s0 + 2; ++s) {
            const unsigned short* base = (s < 2) ? Ab : Bb;
            const int row = ((s & 1) << 7) + srow;
            gload16(base + (size_t)row * K + tt * 32 + scole,
                    (char*)&lds[tt & 3][0] + s * 8192 + tid * 16);
        }
    };

    stage2(0, 0); stage2(0, 2);
    stage2(1, 0); stage2(1, 2);
    stage2(2, 0); stage2(2, 2);

    for (int t = 0; t < nt; ++t) {
        __builtin_amdgcn_sched_barrier(0);
        if (t + 2 < nt)      asm volatile("s_waitcnt vmcnt(8)" ::: "memory");
        else if (t + 1 < nt) asm volatile("s_waitcnt vmcnt(4)" ::: "memory");
        else                 asm volatile("s_waitcnt vmcnt(0)" ::: "memory");
        __builtin_amdgcn_sched_barrier(0);
        __builtin_amdgcn_s_barrier();

        const unsigned short* lb = &lds[t & 3][0];
        s16x8 af[4], bfr[4];
        const int rsw = (fq ^ (fr & 3)) << 3;
        // ---- phase 0: rows wm*128 + 0..63 ----
#pragma unroll
        for (int i = 0; i < 4; ++i)
            af[i] = *(const s16x8*)(lb + (wm * 128 + i * 16 + fr) * 32 + rsw);
#pragma unroll
        for (int n = 0; n < 4; ++n)
            bfr[n] = *(const s16x8*)(lb + 8192 + (wn * 64 + n * 16 + fr) * 32 + rsw);
        if (t + 3 < nt) stage2(t + 3, 0);
        __builtin_amdgcn_s_barrier();
        __builtin_amdgcn_s_setprio(1);
#pragma unroll
        for (int i = 0; i < 4; ++i)
#pragma unroll
            for (int n = 0; n < 4; ++n) acc[i][n] = MFMA16(af[i], bfr[n], acc[i][n]);
        __builtin_amdgcn_s_setprio(0);
        __builtin_amdgcn_s_barrier();
        // ---- phase 1: rows wm*128 + 64..127 (B reused from regs) ----
#pragma unroll
        for (int i = 0; i < 4; ++i)
            af[i] = *(const s16x8*)(lb + (wm * 128 + 64 + i * 16 + fr) * 32 + rsw);
        if (t + 3 < nt) stage2(t + 3, 2);
        __builtin_amdgcn_s_barrier();
        __builtin_amdgcn_s_setprio(1);
#pragma unroll
        for (int i = 0; i < 4; ++i)
#pragma unroll
            for (int n = 0; n < 4; ++n) acc[4 + i][n] = MFMA16(af[i], bfr[n], acc[4 + i][n]);
        __builtin_amdgcn_s_setprio(0);
        __builtin_amdgcn_s_barrier();
    }

#pragma unroll
    for (int a2 = 0; a2 < 8; ++a2) {
        const int row0 = bm * 256 + wm * 128 + ((a2 >> 2) << 6) + ((a2 & 3) << 4) + fq * 4;
#pragma unroll
        for (int n = 0; n < 4; ++n) {
            const int col = bn * 256 + wn * 64 + n * 16 + fr;
            const float bv = (EPI == 3) ? bias[col] : 0.f;
#pragma unroll
            for (int r = 0; r < 4; ++r) {
                float v = acc[a2][n][r] + bv;
                if (EPI == 3) v = fast_gelu(v);
                outp[(size_t)(row0 + r) * N + col] = f2bf(v);
            }
        }
    }
}

// ---------- attention (flash, LDS-staged K/V, swapped QK^T in-lane softmax) ----------
// s[n] = mfma(K_frag, Q_frag) -> lane holds S[kv = n*16+fq*4+r][q = fr]:
// row-max/sum over kv are 15 in-lane ops + 2 shfl_xor (16,32). m,l,alpha are
// per-lane scalars (q=fr). P packed 4 kv (contiguous) per ushort4 -> 4 8B LDS
// writes/tile into PT[q][kv] (XOR-swizzled, same psw as the PV reads).
// alpha/l broadcast to oacc rows (q=fq*4+r) via 4 __shfl.
__global__ __launch_bounds__(256) void attn_kernel(const unsigned short* __restrict__ qkv,
                                                   const unsigned short* __restrict__ vt,
                                                   unsigned short* __restrict__ o) {
    __shared__ __align__(16) unsigned short sK[2][64 * 64];
    __shared__ __align__(16) unsigned short sV[2][64 * 64];
    __shared__ __align__(16) unsigned short sP[4][16 * 64];

    const int j = blockIdx.x;
    const int xcd = j & 7, ix = j >> 3;
    const int bh = xcd * 8 + (ix >> 4);
    const int qt = ix & 15;
    const int b = bh >> 4, h = bh & 15;

    const int tid = threadIdx.x;
    const int wave = tid >> 6, lane = tid & 63;
    const int fr = lane & 15, fq = lane >> 4;

    const unsigned short* kbase = qkv + (size_t)(b * 1024) * 3072 + 1024 + h * 64;
    const unsigned short* vbase = vt + (size_t)bh * 65536;

    const int qrow0 = b * 1024 + qt * 64 + wave * 16;
    const unsigned short* qp = qkv + (size_t)(qrow0 + fr) * 3072 + h * 64;
    const s16x8 aq0 = *(const s16x8*)(qp + fq * 8);
    const s16x8 aq1 = *(const s16x8*)(qp + 32 + fq * 8);

    const f32x4 zero4 = {0.f, 0.f, 0.f, 0.f};
    float m = -1e30f, l = 0.f;
    f32x4 oacc[4];
#pragma unroll
    for (int n = 0; n < 4; ++n) oacc[n] = zero4;

    auto stage = [&](int buf, int kt) {
#pragma unroll
        for (int c = 0; c < 2; ++c) {
            const int ob = tid * 16 + c * 4096;
            const int row = ob >> 7;
            const int slot = (ob >> 4) & 7;
            const int cole = ((slot ^ (row & 7)) << 3);
            gload16(kbase + (size_t)(kt * 64 + row) * 3072 + cole,
                    (char*)&sK[buf][0] + ob);
            gload16(vbase + (size_t)row * 1024 + kt * 64 + cole,
                    (char*)&sV[buf][0] + ob);
        }
    };

    unsigned short* pw = &sP[wave][0];
    const int psw = (fr & 7) << 4;

    stage(0, 0);
    for (int kt = 0; kt < 16; ++kt) {
        const int cur = kt & 1;
        __syncthreads();
        if (kt + 1 < 16) stage(cur ^ 1, kt + 1);

        // ---- QK^T (swapped: A=K, B=Q) ----
        const unsigned short* kb = &sK[cur][0];
        f32x4 s[4];
        __builtin_amdgcn_s_setprio(1);
#pragma unroll
        for (int n = 0; n < 4; ++n) {
            const int R = n * 16 + fr;
            const int sw = (R & 7) << 3;
            const s16x8 bk0 = *(const s16x8*)(kb + R * 64 + ((fq * 8) ^ sw));
            const s16x8 bk1 = *(const s16x8*)(kb + R * 64 + ((32 + fq * 8) ^ sw));
            s[n] = MFMA16(bk0, aq0, zero4);
            s[n] = MFMA16(bk1, aq1, s[n]);
        }
        __builtin_amdgcn_s_setprio(0);

        // ---- online softmax (in-lane over 16 kv, then 2 shfl) ----
        float t0 = fmaxf(fmaxf(s[0][0], s[0][1]), fmaxf(s[0][2], s[0][3]));
        float t1 = fmaxf(fmaxf(s[1][0], s[1][1]), fmaxf(s[1][2], s[1][3]));
        float t2 = fmaxf(fmaxf(s[2][0], s[2][1]), fmaxf(s[2][2], s[2][3]));
        float t3 = fmaxf(fmaxf(s[3][0], s[3][1]), fmaxf(s[3][2], s[3][3]));
        float t = fmaxf(fmaxf(t0, t1), fmaxf(t2, t3)) * SCALE;
        t = fmaxf(t, __shfl_xor(t, 16, 64));
        t = fmaxf(t, __shfl_xor(t, 32, 64));
        const float mnew = fmaxf(m, t);
        const float alpha = __expf(m - mnew);
        float rsum = 0.f;
#pragma unroll
        for (int n = 0; n < 4; ++n) {
            const float p0 = __expf(s[n][0] * SCALE - mnew);
            const float p1 = __expf(s[n][1] * SCALE - mnew);
            const float p2 = __expf(s[n][2] * SCALE - mnew);
            const float p3 = __expf(s[n][3] * SCALE - mnew);
            rsum += (p0 + p1) + (p2 + p3);
            ushort4 pk;
            pk.x = f2bf(p0); pk.y = f2bf(p1); pk.z = f2bf(p2); pk.w = f2bf(p3);
            *(ushort4*)((char*)pw + fr * 128 + ((n * 32 + fq * 8) ^ psw)) = pk;
        }
        rsum += __shfl_xor(rsum, 16, 64);
        rsum += __shfl_xor(rsum, 32, 64);
        l = l * alpha + rsum;
        m = mnew;

        // broadcast alpha to oacc row layout (row q = fq*4+r holds alpha of lane q)
        const float a0 = __shfl(alpha, fq * 4 + 0, 64);
        const float a1 = __shfl(alpha, fq * 4 + 1, 64);
        const float a2 = __shfl(alpha, fq * 4 + 2, 64);
        const float a3 = __shfl(alpha, fq * 4 + 3, 64);
#pragma unroll
        for (int n = 0; n < 4; ++n) {
            oacc[n][0] *= a0; oacc[n][1] *= a1;
            oacc[n][2] *= a2; oacc[n][3] *= a3;
        }

        // ---- PV ---- (P wave-private: lgkmcnt orders write->read)
        const s16x8 ap0 = *(const s16x8*)((char*)pw + fr * 128 + ((fq * 16) ^ psw));
        const s16x8 ap1 = *(const s16x8*)((char*)pw + fr * 128 + ((64 + fq * 16) ^ psw));
        const unsigned short* vb = &sV[cur][0];
        __builtin_amdgcn_s_setprio(1);
#pragma unroll
        for (int n = 0; n < 4; ++n) {
            const int R = n * 16 + fr;
            const int sw = (R & 7) << 3;
            const s16x8 bv0 = *(const s16x8*)(vb + R * 64 + ((fq * 8) ^ sw));
            const s16x8 bv1 = *(const s16x8*)(vb + R * 64 + ((32 + fq * 8) ^ sw));
            oacc[n] = MFMA16(ap0, bv0, oacc[n]);
            oacc[n] = MFMA16(ap1, bv1, oacc[n]);
        }
        __builtin_amdgcn_s_setprio(0);
    }

    const float l0 = __shfl(l, fq * 4 + 0, 64);
    const float l1 = __shfl(l, fq * 4 + 1, 64);
    const float l2 = __shfl(l, fq * 4 + 2, 64);
    const float l3 = __shfl(l, fq * 4 + 3, 64);
    const float rl[4] = {1.f / l0, 1.f / l1, 1.f / l2, 1.f / l3};
#pragma unroll
    for (int r = 0; r < 4; ++r) {
        const int row = qrow0 + fq * 4 + r;
#pragma unroll
        for (int n = 0; n < 4; ++n) {
            const int col = h * 64 + n * 16 + fr;
            o[(size_t)row * 1024 + col] = f2bf(oacc[n][r] * rl[r]);
        }
    }
}

// ---------- launcher ----------
extern "C" void kernel_launch(void* const* d_in, const int* in_sizes, int n_in,
                              void* d_out, int out_size, void* d_ws, size_t ws_size,
                              hipStream_t stream) {
    (void)in_sizes; (void)n_in; (void)out_size; (void)ws_size;
    const float* x      = (const float*)d_in[0];
    const float* skip   = (const float*)d_in[1];
    const float* skip_w = (const float*)d_in[2];
    const float* skip_b = (const float*)d_in[3];
    const float* ln1_g  = (const float*)d_in[4];
    const float* ln1_b  = (const float*)d_in[5];
    const float* qkv_w  = (const float*)d_in[6];
    const float* proj_w = (const float*)d_in[7];
    const float* proj_b = (const float*)d_in[8];
    const float* ln2_g  = (const float*)d_in[9];
    const float* ln2_b  = (const float*)d_in[10];
    const float* fc1_w  = (const float*)d_in[11];
    const float* fc1_b  = (const float*)d_in[12];
    const float* fc2_w  = (const float*)d_in[13];
    const float* fc2_b  = (const float*)d_in[14];
    const float* ln3_g  = (const float*)d_in[15];
    const float* ln3_b  = (const float*)d_in[16];

    char* ws = (char*)d_ws;
    const size_t MB = 1u << 20;
    unsigned short* skip_wT = (unsigned short*)(ws + 0 * MB);    // 4MB  [1024][2048]
    unsigned short* qkv_wT  = (unsigned short*)(ws + 4 * MB);    // 6MB  [3072][1024]
    unsigned short* proj_wT = (unsigned short*)(ws + 10 * MB);   // 2MB  [1024][1024]
    unsigned short* fc1_wT  = (unsigned short*)(ws + 12 * MB);   // 8MB  [4096][1024]
    unsigned short* fc2_wT  = (unsigned short*)(ws + 20 * MB);   // 8MB  [1024][4096]
    float* pre              = (float*)(ws + 28 * MB);            // 16MB [4096][1024] f32
    float* x1               = (float*)(ws + 44 * MB);            // 16MB
    unsigned short* x1b     = (unsigned short*)(ws + 60 * MB);   // 8MB
    unsigned short* qkvb    = (unsigned short*)(ws + 68 * MB);   // 24MB [4096][3072]
    float* x2n              = (float*)(ws + 68 * MB);            // aliases qkvb (dead by LN2)
    unsigned short* x2nb    = (unsigned short*)(ws + 84 * MB);   // 8MB (in old qkvb)
    unsigned short* vtb     = (unsigned short*)(ws + 92 * MB);   // 8MB [64][64][1024]
    unsigned short* ob      = (unsigned short*)(ws + 100 * MB);  // 8MB [4096][1024]
    unsigned short* hb      = (unsigned short*)(ws + 108 * MB);  // 32MB [4096][4096]
    unsigned short* xcatb   = (unsigned short*)(ws + 108 * MB);  // aliases hb (dead by fc1)
    float* outf = (float*)d_out;

    // weight conversions / transposes
    cvt_cat<<<4096, 256, 0, stream>>>(x, skip, xcatb);
    wt_tr<<<512, 256, 0, stream>>>(skip_w, skip_wT, 2048, 1024);
    wt_tr<<<768, 256, 0, stream>>>(qkv_w, qkv_wT, 1024, 3072);
    wt_tr<<<256, 256, 0, stream>>>(proj_w, proj_wT, 1024, 1024);
    wt_tr<<<1024, 256, 0, stream>>>(fc1_w, fc1_wT, 1024, 4096);
    wt_tr<<<1024, 256, 0, stream>>>(fc2_w, fc2_wT, 4096, 1024);

    // skip-cat GEMM -> pre ; LN1 -> x1 (f32) + x1b (bf16)
    gemm128p<0><<<256, 256, 0, stream>>>(xcatb, skip_wT, pre, skip_b, nullptr, 1024, 2048);
    ln_kernel<<<4096, 256, 0, stream>>>(pre, ln1_g, ln1_b, x1, x1b);

    // qkv GEMM (bf16 out, no bias) — 256^2 pipelined
    gemm256<2><<<192, 512, 0, stream>>>(x1b, qkv_wT, qkvb, nullptr, 3072, 1024);

    // attention
    v_transpose<<<1024, 256, 0, stream>>>(qkvb, vtb);
    attn_kernel<<<1024, 256, 0, stream>>>(qkvb, vtb, ob);

    // proj GEMM + bias + residual(x1) -> pre ; LN2 -> x2n + x2nb
    gemm128p<1><<<256, 256, 0, stream>>>(ob, proj_wT, pre, proj_b, x1, 1024, 1024);
    ln_kernel<<<4096, 256, 0, stream>>>(pre, ln2_g, ln2_b, x2n, x2nb);

    // fc1 GEMM + bias + GELU -> h (bf16) — 256^2 pipelined
    gemm256<3><<<256, 512, 0, stream>>>(x2nb, fc1_wT, hb, fc1_b, 4096, 1024);

    // fc2 GEMM + bias + residual(x2n) -> pre ; LN3 -> d_out (f32)
    gemm128p<1><<<256, 256, 0, stream>>>(hb, fc2_wT, pre, fc2_b, x2n, 1024, 4096);
    ln_kernel<<<4096, 256, 0, stream>>>(pre, ln3_g, ln3_b, outf, nullptr);
}